// Round 13
// baseline (56.931 us; speedup 1.0000x reference)
//
#include <hip/hip_runtime.h>

#define DIM       128
#define BATCH     16384
#define RELN      500
#define ALPHA     0.001f
#define CHUNK     8
#define MAXCHUNKS (BATCH / CHUNK + RELN)   // 2548 chunk slots (padded)
#define NHB       64                       // hist/scatter blocks (256 elems each)

__device__ __forceinline__ float dot4(float4 a, float4 b) {
    return a.x * b.x + a.y * b.y + a.z * b.z + a.w * b.w;
}

// ---------- K1: own-slice histogram -> BIN-MAJOR partials ----------
__global__ void __launch_bounds__(256) hist_kernel(
    const int* __restrict__ r_idx,
    int*       __restrict__ partialT)    // [512][NHB] bin-major
{
    __shared__ int cnt[512];
    const int tid = threadIdx.x;
    cnt[tid] = 0; cnt[tid + 256] = 0;
    __syncthreads();
    atomicAdd(&cnt[r_idx[blockIdx.x * 256 + tid]], 1);
    __syncthreads();
    partialT[tid * NHB + blockIdx.x]         = cnt[tid];
    partialT[(tid + 256) * NHB + blockIdx.x] = cnt[tid + 256];
}

// ---------- K2: scatter (redundant per-block scan, all LDS/regs) ----------
__global__ void __launch_bounds__(256) scatter_kernel(
    const int*   __restrict__ r_idx,
    const int*   __restrict__ h_idx,
    const int*   __restrict__ t_idx,
    const float* __restrict__ labels,
    const int*   __restrict__ partialT,   // [512][NHB]
    int4*        __restrict__ quad,       // [BATCH] (h, t, b, label_bits)
    int4*        __restrict__ chunk_info) // [MAXCHUNKS] (rel, start, e_cnt, 0)
{
    __shared__ int sc[512];
    __shared__ int boff[512];
    __shared__ int lcnt[512];
    const int tid = threadIdx.x;
    const int bid = blockIdx.x;

    // per-bin total + prefix(b < bid), contiguous int4 reads
    const int4* row0 = (const int4*)(partialT + tid * NHB);
    const int4* row1 = (const int4*)(partialT + (tid + 256) * NHB);
    int tot0 = 0, pre0 = 0, tot1 = 0, pre1 = 0;
    #pragma unroll
    for (int k = 0; k < 16; ++k) {
        const int4 v0 = row0[k];
        const int4 v1 = row1[k];
        tot0 += v0.x + v0.y + v0.z + v0.w;
        tot1 += v1.x + v1.y + v1.z + v1.w;
        const int b = 4 * k;
        pre0 += (b < bid ? v0.x : 0) + (b + 1 < bid ? v0.y : 0)
              + (b + 2 < bid ? v0.z : 0) + (b + 3 < bid ? v0.w : 0);
        pre1 += (b < bid ? v1.x : 0) + (b + 1 < bid ? v1.y : 0)
              + (b + 2 < bid ? v1.z : 0) + (b + 3 < bid ? v1.w : 0);
    }

    // 512-wide inclusive scan (2 elems/thread Hillis-Steele)
    sc[tid] = tot0; sc[tid + 256] = tot1;
    __syncthreads();
    for (int d = 1; d < 512; d <<= 1) {
        const int x0 = (tid >= d) ? sc[tid - d] : 0;
        const int x1 = (tid + 256 >= d) ? sc[tid + 256 - d] : 0;
        __syncthreads();
        sc[tid] += x0; sc[tid + 256] += x1;
        __syncthreads();
    }
    const int excl0 = sc[tid] - tot0;
    const int excl1 = sc[tid + 256] - tot1;
    boff[tid]       = excl0 + pre0;
    boff[tid + 256] = excl1 + pre1;
    lcnt[tid] = 0; lcnt[tid + 256] = 0;
    __syncthreads();

    // scatter own element
    {
        const int i   = bid * 256 + tid;
        const int r   = r_idx[i];
        const int pos = boff[r] + atomicAdd(&lcnt[r], 1);
        quad[pos] = make_int4(h_idx[i], t_idx[i], i, __float_as_int(labels[i]));
    }

    // block NHB-1: chunk_info (+ zero tail). Uniform branch; barriers OK.
    if (bid == NHB - 1) {
        const int nc0 = (tot0 + CHUNK - 1) / CHUNK;            // bins 0..255 < RELN
        const int nc1 = (tid + 256 < RELN) ? (tot1 + CHUNK - 1) / CHUNK : 0;
        __syncthreads();
        sc[tid] = nc0; sc[tid + 256] = nc1;
        __syncthreads();
        for (int d = 1; d < 512; d <<= 1) {
            const int x0 = (tid >= d) ? sc[tid - d] : 0;
            const int x1 = (tid + 256 >= d) ? sc[tid + 256 - d] : 0;
            __syncthreads();
            sc[tid] += x0; sc[tid + 256] += x1;
            __syncthreads();
        }
        const int cb0   = sc[tid] - nc0;
        const int cb1   = sc[tid + 256] - nc1;
        const int total = sc[511];
        for (int i = 0; i < nc0; ++i)
            chunk_info[cb0 + i] = make_int4(tid, excl0 + i * CHUNK,
                                            min(CHUNK, tot0 - i * CHUNK), 0);
        for (int i = 0; i < nc1; ++i)
            chunk_info[cb1 + i] = make_int4(tid + 256, excl1 + i * CHUNK,
                                            min(CHUNK, tot1 - i * CHUNK), 0);
        for (int p = total + tid; p < MAXCHUNKS; p += 256)
            chunk_info[p] = make_int4(0, 0, 0, 0);
    }
}

// ---------- K3: main — software-pipelined R stream (double-buffered groups) ----------
// Per thread: rows rbase..rbase+15 (rbase=32w+16hi), float4 col slice c4.
// 4-row groups double-buffered in registers with STATIC indices: issue loads
// for group k+1, then compute group k — exposed L2 latency drops 4x vs the
// previous serial unroll-1 stream (R12 post-mortem: main ~37us, VALUBusy 12%,
// latency-bound). VGPR target ~80-95 (5-6 waves/SIMD).
__global__ void __launch_bounds__(256) rescal_main_kernel(
    const int4*  __restrict__ chunk_info,
    const int4*  __restrict__ quad,
    const float* __restrict__ ent_w,
    const float* __restrict__ rel_w,
    float*       __restrict__ scores_out,   // d_out + 1
    float4*      __restrict__ chunk_out)    // [MAXCHUNKS] (errS, htS, cnt*r2, 0)
{
    // bijective XCD swizzle: consecutive cids (same relation) share an XCD L2
    const int bid = blockIdx.x;
    const int xcd = bid & 7;
    const int j   = bid >> 3;
    const int q   = MAXCHUNKS / 8;
    const int r_  = MAXCHUNKS % 8;
    const int cid = (xcd < r_ ? xcd * (q + 1) : r_ * (q + 1) + (xcd - r_) * q) + j;

    const int tid = threadIdx.x;

    const int4 ci    = chunk_info[cid];
    const int  rel   = ci.x;
    const int  start = ci.y;
    const int  e_cnt = ci.z;
    if (e_cnt == 0) {                        // padded slot: zero for final's pass
        if (tid == 0) chunk_out[cid] = make_float4(0.f, 0.f, 0.f, 0.f);
        return;
    }

    const int w   = tid >> 6;
    const int l   = tid & 63;
    const int hi  = l >> 5;
    const int c4  = l & 31;
    const int rbase = 32 * w + 16 * hi;

    __shared__ float t_lds[CHUNK][DIM];
    __shared__ float h_lds[CHUNK][DIM];
    __shared__ float red[4][CHUNK];
    __shared__ float ht_red[CHUNK];
    __shared__ float d2s[CHUNK];
    __shared__ float r2_red[4];

    const float4* Rb = (const float4*)(rel_w + (size_t)rel * (DIM * DIM)
                                             + (size_t)rbase * DIM) + c4;

    // issue group-0 R loads FIRST (overlap with t/h staging)
    float4 a0, a1, a2, a3, b0, b1, b2, b3;
    a0 = Rb[0 * (DIM / 4)];
    a1 = Rb[1 * (DIM / 4)];
    a2 = Rb[2 * (DIM / 4)];
    a3 = Rb[3 * (DIM / 4)];

    // stage t, h (32 threads per element, 1 float4 each)
    const int eg   = tid >> 5;
    const int col4 = tid & 31;
    float4 tv4 = make_float4(0.f, 0.f, 0.f, 0.f);
    float4 hv4 = tv4;
    if (eg < e_cnt) {
        const int4 qd = quad[start + eg];
        hv4 = *(const float4*)(ent_w + (size_t)qd.x * DIM + col4 * 4);
        tv4 = *(const float4*)(ent_w + (size_t)qd.y * DIM + col4 * 4);
    }
    *(float4*)&t_lds[eg][col4 * 4] = tv4;
    *(float4*)&h_lds[eg][col4 * 4] = hv4;

    float htp = dot4(tv4, tv4) + dot4(hv4, hv4);
    #pragma unroll
    for (int off = 16; off >= 1; off >>= 1) htp += __shfl_xor(htp, off);
    if ((tid & 31) == 0) ht_red[eg] = htp;
    __syncthreads();

    // t fragments to registers (b128, conflict-free)
    float4 t4[CHUNK];
    #pragma unroll
    for (int e = 0; e < CHUNK; ++e)
        t4[e] = *(const float4*)&t_lds[e][c4 * 4];

    float acc[CHUNK];
    #pragma unroll
    for (int e = 0; e < CHUNK; ++e) acc[e] = 0.f;
    float r2 = 0.f;

    // ---- software-pipelined groups: load(k+1) then compute(k), static regs ----
    #define LOADB(g)  b0 = Rb[(4*(g)+0)*(DIM/4)]; b1 = Rb[(4*(g)+1)*(DIM/4)]; \
                      b2 = Rb[(4*(g)+2)*(DIM/4)]; b3 = Rb[(4*(g)+3)*(DIM/4)];
    #define LOADA(g)  a0 = Rb[(4*(g)+0)*(DIM/4)]; a1 = Rb[(4*(g)+1)*(DIM/4)]; \
                      a2 = Rb[(4*(g)+2)*(DIM/4)]; a3 = Rb[(4*(g)+3)*(DIM/4)];
    #define COMP(r0, r1, rr2_, r3, pg)                                         \
        r2 += dot4(r0, r0) + dot4(r1, r1) + dot4(rr2_, rr2_) + dot4(r3, r3);   \
        _Pragma("unroll")                                                      \
        for (int e = 0; e < CHUNK; ++e) {                                      \
            const float4 h4 = *(const float4*)&h_lds[e][rbase + 4 * (pg)];     \
            acc[e] += h4.x * dot4(r0, t4[e]) + h4.y * dot4(r1, t4[e])          \
                    + h4.z * dot4(rr2_, t4[e]) + h4.w * dot4(r3, t4[e]);       \
        }

    LOADB(1); COMP(a0, a1, a2, a3, 0);
    LOADA(2); COMP(b0, b1, b2, b3, 1);
    LOADB(3); COMP(a0, a1, a2, a3, 2);
              COMP(b0, b1, b2, b3, 3);
    #undef LOADB
    #undef LOADA
    #undef COMP

    // reductions (slot-invariant trees -> scores bit-stable)
    #pragma unroll
    for (int off = 32; off >= 1; off >>= 1) r2 += __shfl_xor(r2, off);
    if (l == 0) r2_red[w] = r2;

    #pragma unroll
    for (int e = 0; e < CHUNK; ++e) {
        float v = acc[e];
        #pragma unroll
        for (int off = 32; off >= 1; off >>= 1) v += __shfl_xor(v, off);
        if (l == 0) red[w][e] = v;
    }
    __syncthreads();

    if (tid < e_cnt) {
        const float s  = red[0][tid] + red[1][tid] + red[2][tid] + red[3][tid];
        const int4 qd  = quad[start + tid];
        scores_out[qd.z] = s;
        const float d  = s - __int_as_float(qd.w);
        d2s[tid] = d * d;
    }
    __syncthreads();

    if (tid == 0) {
        float err = 0.f, ht = 0.f;
        for (int e = 0; e < e_cnt; ++e) { err += d2s[e]; ht += ht_red[e]; }
        const float r2t = r2_red[0] + r2_red[1] + r2_red[2] + r2_red[3];
        chunk_out[cid] = make_float4(err, ht, (float)e_cnt * r2t, 0.f);
    }
}

// ---------- K4: final — fixed-order reduction over full chunk_out -> loss ----------
__global__ void __launch_bounds__(256) final_kernel(
    const float4* __restrict__ chunk_out,
    float*        __restrict__ loss_out)
{
    const int tid = threadIdx.x;
    float err = 0.f, ht = 0.f, r2 = 0.f;
    for (int i = tid; i < MAXCHUNKS; i += 256) {
        const float4 c = chunk_out[i];
        err += c.x; ht += c.y; r2 += c.z;
    }
    __shared__ float re[4], rh[4], rr2[4];
    #pragma unroll
    for (int off = 32; off >= 1; off >>= 1) {
        err += __shfl_down(err, off);
        ht  += __shfl_down(ht, off);
        r2  += __shfl_down(r2, off);
    }
    if ((tid & 63) == 0) { const int v = tid >> 6; re[v] = err; rh[v] = ht; rr2[v] = r2; }
    __syncthreads();
    if (tid == 0) {
        err = re[0] + re[1] + re[2] + re[3];
        ht  = rh[0] + rh[1] + rh[2] + rh[3];
        r2  = rr2[0] + rr2[1] + rr2[2] + rr2[3];
        const float mse   = err / (float)BATCH;
        const float norms = (ht / ((float)BATCH * DIM)
                           + r2 / ((float)BATCH * (float)(DIM * DIM))) / 3.0f;
        loss_out[0] = mse + ALPHA * norms;
    }
}

extern "C" void kernel_launch(void* const* d_in, const int* in_sizes, int n_in,
                              void* d_out, int out_size, void* d_ws, size_t ws_size,
                              hipStream_t stream) {
    const int*   h_idx  = (const int*)d_in[0];
    const int*   r_idx  = (const int*)d_in[1];
    const int*   t_idx  = (const int*)d_in[2];
    const float* labels = (const float*)d_in[3];
    const float* ent_w  = (const float*)d_in[4];
    const float* rel_w  = (const float*)d_in[5];

    float* out = (float*)d_out;   // [0]=loss, [1..BATCH]=scores

    // workspace layout (~470 KB)
    char* ws = (char*)d_ws;
    int4*   quad       = (int4*)ws;             ws += BATCH * sizeof(int4);        // 256K
    int*    partialT   = (int*)ws;              ws += 512 * NHB * sizeof(int);     // 128K
    int4*   chunk_info = (int4*)ws;             ws += MAXCHUNKS * sizeof(int4);    // ~41K
    float4* chunk_out  = (float4*)ws;           // ~41K

    hist_kernel<<<NHB, 256, 0, stream>>>(r_idx, partialT);
    scatter_kernel<<<NHB, 256, 0, stream>>>(r_idx, h_idx, t_idx, labels,
                                            partialT, quad, chunk_info);
    rescal_main_kernel<<<MAXCHUNKS, 256, 0, stream>>>(
        chunk_info, quad, ent_w, rel_w, out + 1, chunk_out);
    final_kernel<<<1, 256, 0, stream>>>(chunk_out, out);
}

// Round 14
// 56.840 us; speedup vs baseline: 1.0016x; 1.0016x over previous
//
#include <hip/hip_runtime.h>

#define DIM       128
#define BATCH     16384
#define RELN      500
#define ALPHA     0.001f
#define CHUNK     8
#define MAXCHUNKS (BATCH / CHUNK + RELN)   // 2548 chunk slots (padded)
#define NHB       64                       // hist/scatter blocks (256 elems each)
#define MGRID     1024                     // main grid (4 blocks/CU)

__device__ __forceinline__ float dot4(float4 a, float4 b) {
    return a.x * b.x + a.y * b.y + a.z * b.z + a.w * b.w;
}

// ---------- K1: own-slice histogram -> BIN-MAJOR partials ----------
__global__ void __launch_bounds__(256) hist_kernel(
    const int* __restrict__ r_idx,
    int*       __restrict__ partialT)    // [512][NHB] bin-major
{
    __shared__ int cnt[512];
    const int tid = threadIdx.x;
    cnt[tid] = 0; cnt[tid + 256] = 0;
    __syncthreads();
    atomicAdd(&cnt[r_idx[blockIdx.x * 256 + tid]], 1);
    __syncthreads();
    partialT[tid * NHB + blockIdx.x]         = cnt[tid];
    partialT[(tid + 256) * NHB + blockIdx.x] = cnt[tid + 256];
}

// ---------- K2: scatter (redundant per-block scan, all LDS/regs) ----------
__global__ void __launch_bounds__(256) scatter_kernel(
    const int*   __restrict__ r_idx,
    const int*   __restrict__ h_idx,
    const int*   __restrict__ t_idx,
    const float* __restrict__ labels,
    const int*   __restrict__ partialT,   // [512][NHB]
    int4*        __restrict__ quad,       // [BATCH] (h, t, b, label_bits)
    int4*        __restrict__ chunk_info) // [MAXCHUNKS] (rel, start, e_cnt, 0)
{
    __shared__ int sc[512];
    __shared__ int boff[512];
    __shared__ int lcnt[512];
    const int tid = threadIdx.x;
    const int bid = blockIdx.x;

    const int4* row0 = (const int4*)(partialT + tid * NHB);
    const int4* row1 = (const int4*)(partialT + (tid + 256) * NHB);
    int tot0 = 0, pre0 = 0, tot1 = 0, pre1 = 0;
    #pragma unroll
    for (int k = 0; k < 16; ++k) {
        const int4 v0 = row0[k];
        const int4 v1 = row1[k];
        tot0 += v0.x + v0.y + v0.z + v0.w;
        tot1 += v1.x + v1.y + v1.z + v1.w;
        const int b = 4 * k;
        pre0 += (b < bid ? v0.x : 0) + (b + 1 < bid ? v0.y : 0)
              + (b + 2 < bid ? v0.z : 0) + (b + 3 < bid ? v0.w : 0);
        pre1 += (b < bid ? v1.x : 0) + (b + 1 < bid ? v1.y : 0)
              + (b + 2 < bid ? v1.z : 0) + (b + 3 < bid ? v1.w : 0);
    }

    sc[tid] = tot0; sc[tid + 256] = tot1;
    __syncthreads();
    for (int d = 1; d < 512; d <<= 1) {
        const int x0 = (tid >= d) ? sc[tid - d] : 0;
        const int x1 = (tid + 256 >= d) ? sc[tid + 256 - d] : 0;
        __syncthreads();
        sc[tid] += x0; sc[tid + 256] += x1;
        __syncthreads();
    }
    const int excl0 = sc[tid] - tot0;
    const int excl1 = sc[tid + 256] - tot1;
    boff[tid]       = excl0 + pre0;
    boff[tid + 256] = excl1 + pre1;
    lcnt[tid] = 0; lcnt[tid + 256] = 0;
    __syncthreads();

    {
        const int i   = bid * 256 + tid;
        const int r   = r_idx[i];
        const int pos = boff[r] + atomicAdd(&lcnt[r], 1);
        quad[pos] = make_int4(h_idx[i], t_idx[i], i, __float_as_int(labels[i]));
    }

    if (bid == NHB - 1) {
        const int nc0 = (tot0 + CHUNK - 1) / CHUNK;
        const int nc1 = (tid + 256 < RELN) ? (tot1 + CHUNK - 1) / CHUNK : 0;
        __syncthreads();
        sc[tid] = nc0; sc[tid + 256] = nc1;
        __syncthreads();
        for (int d = 1; d < 512; d <<= 1) {
            const int x0 = (tid >= d) ? sc[tid - d] : 0;
            const int x1 = (tid + 256 >= d) ? sc[tid + 256 - d] : 0;
            __syncthreads();
            sc[tid] += x0; sc[tid + 256] += x1;
            __syncthreads();
        }
        const int cb0   = sc[tid] - nc0;
        const int cb1   = sc[tid + 256] - nc1;
        const int total = sc[511];
        for (int i = 0; i < nc0; ++i)
            chunk_info[cb0 + i] = make_int4(tid, excl0 + i * CHUNK,
                                            min(CHUNK, tot0 - i * CHUNK), 0);
        for (int i = 0; i < nc1; ++i)
            chunk_info[cb1 + i] = make_int4(tid + 256, excl1 + i * CHUNK,
                                            min(CHUNK, tot1 - i * CHUNK), 0);
        for (int p = total + tid; p < MAXCHUNKS; p += 256)
            chunk_info[p] = make_int4(0, 0, 0, 0);
    }
}

// ---------- K3: main — grid-stride, 8-row R groups (unroll 1), t from LDS ----------
// Grid 1024 (4 blocks/CU steady); each block ~2.5 chunk slots. Per half:
// 8 outstanding b128 R loads (2x R12's MLP); t re-read from LDS per (half,e)
// keeps VGPR ~70 (8 waves/SIMD). Next slot's chunk_info prefetched to regs.
__global__ void __launch_bounds__(256) rescal_main_kernel(
    const int4*  __restrict__ chunk_info,
    const int4*  __restrict__ quad,
    const float* __restrict__ ent_w,
    const float* __restrict__ rel_w,
    float*       __restrict__ scores_out,   // d_out + 1
    float4*      __restrict__ chunk_out)    // [MAXCHUNKS] (errS, htS, cnt*r2, 0)
{
    const int tid = threadIdx.x;
    const int w   = tid >> 6;
    const int l   = tid & 63;
    const int hi  = l >> 5;
    const int c4  = l & 31;
    const int rbase = 32 * w + 16 * hi;
    const int eg   = tid >> 5;
    const int col4 = tid & 31;

    __shared__ float t_lds[CHUNK][DIM];
    __shared__ float h_lds[CHUNK][DIM];
    __shared__ float red[4][CHUNK];
    __shared__ float ht_red[CHUNK];
    __shared__ float d2s[CHUNK];
    __shared__ float r2_red[4];

    // bijective XCD swizzle over slot space
    #define SWZ(k) ((((k) & 7) < (MAXCHUNKS % 8)                                   \
                      ? ((k) & 7) * (MAXCHUNKS / 8 + 1)                            \
                      : (MAXCHUNKS % 8) * (MAXCHUNKS / 8 + 1)                      \
                        + (((k) & 7) - (MAXCHUNKS % 8)) * (MAXCHUNKS / 8))         \
                    + ((k) >> 3))

    int  cid = SWZ(blockIdx.x);
    int4 ci  = chunk_info[cid];                  // prefetched descriptor

    for (int k = blockIdx.x; k < MAXCHUNKS; k += MGRID) {
        const int kn = k + MGRID;
        const int cid_next = (kn < MAXCHUNKS) ? SWZ(kn) : 0;

        const int rel   = ci.x;
        const int start = ci.y;
        const int e_cnt = ci.z;                  // block-uniform

        if (e_cnt == 0) {
            if (tid == 0) chunk_out[cid] = make_float4(0.f, 0.f, 0.f, 0.f);
            if (kn < MAXCHUNKS) ci = chunk_info[cid_next];
            cid = cid_next;
            continue;
        }

        // stage t, h (32 threads per element, 1 float4 each)
        float4 tv4 = make_float4(0.f, 0.f, 0.f, 0.f);
        float4 hv4 = tv4;
        if (eg < e_cnt) {
            const int4 qd = quad[start + eg];
            hv4 = *(const float4*)(ent_w + (size_t)qd.x * DIM + col4 * 4);
            tv4 = *(const float4*)(ent_w + (size_t)qd.y * DIM + col4 * 4);
        }
        *(float4*)&t_lds[eg][col4 * 4] = tv4;
        *(float4*)&h_lds[eg][col4 * 4] = hv4;

        float htp = dot4(tv4, tv4) + dot4(hv4, hv4);
        #pragma unroll
        for (int off = 16; off >= 1; off >>= 1) htp += __shfl_xor(htp, off);
        if ((tid & 31) == 0) ht_red[eg] = htp;

        // prefetch next slot's descriptor (overlaps barrier + compute)
        if (kn < MAXCHUNKS) ci = chunk_info[cid_next];
        __syncthreads();

        // ---- stream R: two 8-row halves, unroll 1 (rA[8] = 32 VGPR live) ----
        const float4* Rb = (const float4*)(rel_w + (size_t)rel * (DIM * DIM)
                                                 + (size_t)rbase * DIM) + c4;
        float acc[CHUNK];
        #pragma unroll
        for (int e = 0; e < CHUNK; ++e) acc[e] = 0.f;
        float r2 = 0.f;

        #pragma unroll 1
        for (int half = 0; half < 2; ++half) {
            float4 rA[8];
            #pragma unroll
            for (int p = 0; p < 8; ++p)
                rA[p] = Rb[(8 * half + p) * (DIM / 4)];
            #pragma unroll
            for (int p = 0; p < 8; ++p) r2 += dot4(rA[p], rA[p]);
            #pragma unroll
            for (int e = 0; e < CHUNK; ++e) {
                const float4 te = *(const float4*)&t_lds[e][c4 * 4];
                const float4 h0 = *(const float4*)&h_lds[e][rbase + 8 * half];
                const float4 h1 = *(const float4*)&h_lds[e][rbase + 8 * half + 4];
                acc[e] += h0.x * dot4(rA[0], te) + h0.y * dot4(rA[1], te)
                        + h0.z * dot4(rA[2], te) + h0.w * dot4(rA[3], te)
                        + h1.x * dot4(rA[4], te) + h1.y * dot4(rA[5], te)
                        + h1.z * dot4(rA[6], te) + h1.w * dot4(rA[7], te);
            }
        }

        // reductions (slot-invariant trees -> scores bit-stable)
        #pragma unroll
        for (int off = 32; off >= 1; off >>= 1) r2 += __shfl_xor(r2, off);
        if (l == 0) r2_red[w] = r2;

        #pragma unroll
        for (int e = 0; e < CHUNK; ++e) {
            float v = acc[e];
            #pragma unroll
            for (int off = 32; off >= 1; off >>= 1) v += __shfl_xor(v, off);
            if (l == 0) red[w][e] = v;
        }
        __syncthreads();

        if (tid < e_cnt) {
            const float s  = red[0][tid] + red[1][tid] + red[2][tid] + red[3][tid];
            const int4 qd  = quad[start + tid];
            scores_out[qd.z] = s;
            const float d  = s - __int_as_float(qd.w);
            d2s[tid] = d * d;
        }
        __syncthreads();

        if (tid == 0) {
            float err = 0.f, ht = 0.f;
            for (int e = 0; e < e_cnt; ++e) { err += d2s[e]; ht += ht_red[e]; }
            const float r2t = r2_red[0] + r2_red[1] + r2_red[2] + r2_red[3];
            chunk_out[cid] = make_float4(err, ht, (float)e_cnt * r2t, 0.f);
        }
        __syncthreads();   // protect LDS before next iteration overwrites
        cid = cid_next;
    }
    #undef SWZ
}

// ---------- K4: final — fixed-order reduction over full chunk_out -> loss ----------
__global__ void __launch_bounds__(256) final_kernel(
    const float4* __restrict__ chunk_out,
    float*        __restrict__ loss_out)
{
    const int tid = threadIdx.x;
    float err = 0.f, ht = 0.f, r2 = 0.f;
    for (int i = tid; i < MAXCHUNKS; i += 256) {
        const float4 c = chunk_out[i];
        err += c.x; ht += c.y; r2 += c.z;
    }
    __shared__ float re[4], rh[4], rr2[4];
    #pragma unroll
    for (int off = 32; off >= 1; off >>= 1) {
        err += __shfl_down(err, off);
        ht  += __shfl_down(ht, off);
        r2  += __shfl_down(r2, off);
    }
    if ((tid & 63) == 0) { const int v = tid >> 6; re[v] = err; rh[v] = ht; rr2[v] = r2; }
    __syncthreads();
    if (tid == 0) {
        err = re[0] + re[1] + re[2] + re[3];
        ht  = rh[0] + rh[1] + rh[2] + rh[3];
        r2  = rr2[0] + rr2[1] + rr2[2] + rr2[3];
        const float mse   = err / (float)BATCH;
        const float norms = (ht / ((float)BATCH * DIM)
                           + r2 / ((float)BATCH * (float)(DIM * DIM))) / 3.0f;
        loss_out[0] = mse + ALPHA * norms;
    }
}

extern "C" void kernel_launch(void* const* d_in, const int* in_sizes, int n_in,
                              void* d_out, int out_size, void* d_ws, size_t ws_size,
                              hipStream_t stream) {
    const int*   h_idx  = (const int*)d_in[0];
    const int*   r_idx  = (const int*)d_in[1];
    const int*   t_idx  = (const int*)d_in[2];
    const float* labels = (const float*)d_in[3];
    const float* ent_w  = (const float*)d_in[4];
    const float* rel_w  = (const float*)d_in[5];

    float* out = (float*)d_out;   // [0]=loss, [1..BATCH]=scores

    // workspace layout (~470 KB)
    char* ws = (char*)d_ws;
    int4*   quad       = (int4*)ws;             ws += BATCH * sizeof(int4);        // 256K
    int*    partialT   = (int*)ws;              ws += 512 * NHB * sizeof(int);     // 128K
    int4*   chunk_info = (int4*)ws;             ws += MAXCHUNKS * sizeof(int4);    // ~41K
    float4* chunk_out  = (float4*)ws;           // ~41K

    hist_kernel<<<NHB, 256, 0, stream>>>(r_idx, partialT);
    scatter_kernel<<<NHB, 256, 0, stream>>>(r_idx, h_idx, t_idx, labels,
                                            partialT, quad, chunk_info);
    rescal_main_kernel<<<MGRID, 256, 0, stream>>>(
        chunk_info, quad, ent_w, rel_w, out + 1, chunk_out);
    final_kernel<<<1, 256, 0, stream>>>(chunk_out, out);
}

// Round 15
// 56.727 us; speedup vs baseline: 1.0036x; 1.0020x over previous
//
#include <hip/hip_runtime.h>

#define DIM       128
#define BATCH     16384
#define RELN      500
#define ALPHA     0.001f
#define CHUNK     16
#define MAXCHUNKS (BATCH / CHUNK + RELN)   // 1524 slot upper bound (ws sizing)
#define NHB       64                       // hist/scatter blocks (256 elems each)
#define MGRID     1024                     // main grid (persistent, 4 blocks/CU)

__device__ __forceinline__ float dot4(float4 a, float4 b) {
    return a.x * b.x + a.y * b.y + a.z * b.z + a.w * b.w;
}

// ---------- K1: own-slice histogram -> BIN-MAJOR partials ----------
__global__ void __launch_bounds__(256) hist_kernel(
    const int* __restrict__ r_idx,
    int*       __restrict__ partialT)    // [512][NHB] bin-major
{
    __shared__ int cnt[512];
    const int tid = threadIdx.x;
    cnt[tid] = 0; cnt[tid + 256] = 0;
    __syncthreads();
    atomicAdd(&cnt[r_idx[blockIdx.x * 256 + tid]], 1);
    __syncthreads();
    partialT[tid * NHB + blockIdx.x]         = cnt[tid];
    partialT[(tid + 256) * NHB + blockIdx.x] = cnt[tid + 256];
}

// ---------- K2: scatter (redundant per-block scan) + compacted chunk list ----------
__global__ void __launch_bounds__(256) scatter_kernel(
    const int*   __restrict__ r_idx,
    const int*   __restrict__ h_idx,
    const int*   __restrict__ t_idx,
    const float* __restrict__ labels,
    const int*   __restrict__ partialT,   // [512][NHB]
    int4*        __restrict__ quad,       // [BATCH] (h, t, b, label_bits)
    int4*        __restrict__ chunk_info, // [<=MAXCHUNKS] (rel, start, e_cnt, 0)
    int*         __restrict__ n_chunks)   // [1]
{
    __shared__ int sc[512];
    __shared__ int boff[512];
    __shared__ int lcnt[512];
    const int tid = threadIdx.x;
    const int bid = blockIdx.x;

    const int4* row0 = (const int4*)(partialT + tid * NHB);
    const int4* row1 = (const int4*)(partialT + (tid + 256) * NHB);
    int tot0 = 0, pre0 = 0, tot1 = 0, pre1 = 0;
    #pragma unroll
    for (int k = 0; k < 16; ++k) {
        const int4 v0 = row0[k];
        const int4 v1 = row1[k];
        tot0 += v0.x + v0.y + v0.z + v0.w;
        tot1 += v1.x + v1.y + v1.z + v1.w;
        const int b = 4 * k;
        pre0 += (b < bid ? v0.x : 0) + (b + 1 < bid ? v0.y : 0)
              + (b + 2 < bid ? v0.z : 0) + (b + 3 < bid ? v0.w : 0);
        pre1 += (b < bid ? v1.x : 0) + (b + 1 < bid ? v1.y : 0)
              + (b + 2 < bid ? v1.z : 0) + (b + 3 < bid ? v1.w : 0);
    }

    sc[tid] = tot0; sc[tid + 256] = tot1;
    __syncthreads();
    for (int d = 1; d < 512; d <<= 1) {
        const int x0 = (tid >= d) ? sc[tid - d] : 0;
        const int x1 = (tid + 256 >= d) ? sc[tid + 256 - d] : 0;
        __syncthreads();
        sc[tid] += x0; sc[tid + 256] += x1;
        __syncthreads();
    }
    const int excl0 = sc[tid] - tot0;
    const int excl1 = sc[tid + 256] - tot1;
    boff[tid]       = excl0 + pre0;
    boff[tid + 256] = excl1 + pre1;
    lcnt[tid] = 0; lcnt[tid + 256] = 0;
    __syncthreads();

    {
        const int i   = bid * 256 + tid;
        const int r   = r_idx[i];
        const int pos = boff[r] + atomicAdd(&lcnt[r], 1);
        quad[pos] = make_int4(h_idx[i], t_idx[i], i, __float_as_int(labels[i]));
    }

    if (bid == NHB - 1) {
        const int nc0 = (tot0 + CHUNK - 1) / CHUNK;
        const int nc1 = (tid + 256 < RELN) ? (tot1 + CHUNK - 1) / CHUNK : 0;
        __syncthreads();
        sc[tid] = nc0; sc[tid + 256] = nc1;
        __syncthreads();
        for (int d = 1; d < 512; d <<= 1) {
            const int x0 = (tid >= d) ? sc[tid - d] : 0;
            const int x1 = (tid + 256 >= d) ? sc[tid + 256 - d] : 0;
            __syncthreads();
            sc[tid] += x0; sc[tid + 256] += x1;
            __syncthreads();
        }
        const int cb0 = sc[tid] - nc0;
        const int cb1 = sc[tid + 256] - nc1;
        for (int i = 0; i < nc0; ++i)
            chunk_info[cb0 + i] = make_int4(tid, excl0 + i * CHUNK,
                                            min(CHUNK, tot0 - i * CHUNK), 0);
        for (int i = 0; i < nc1; ++i)
            chunk_info[cb1 + i] = make_int4(tid + 256, excl1 + i * CHUNK,
                                            min(CHUNK, tot1 - i * CHUNK), 0);
        if (tid == 255) n_chunks[0] = sc[511];
    }
}

// ---------- K3: main — grid-stride persistent, CHUNK=16, 2 barriers/chunk ----------
// Thread (w,hi,c4): 16 consecutive rows rbase=32w+16hi, float4 col slice c4.
// R streamed as two 8-row halves (unroll 1, rA[8]=32 VGPR live); t re-read
// from LDS per half; h via 2-address broadcast b128. Tail reduction is
// shfl-only in wave 0 (htr pre-read before 2nd barrier kills the 3rd barrier).
__global__ void __launch_bounds__(256) rescal_main_kernel(
    const int4*  __restrict__ chunk_info,
    const int4*  __restrict__ quad,
    const float* __restrict__ ent_w,
    const float* __restrict__ rel_w,
    const int*   __restrict__ n_chunks,
    float*       __restrict__ scores_out,   // d_out + 1
    float4*      __restrict__ chunk_out)    // [total] (errS, htS, cnt*r2, 0)
{
    const int tid = threadIdx.x;
    const int w   = tid >> 6;
    const int l   = tid & 63;
    const int hi  = l >> 5;
    const int c4  = l & 31;
    const int rbase = 32 * w + 16 * hi;
    const int eg   = tid >> 4;          // staging element 0..15
    const int sub  = tid & 15;          // 16 threads/element, 32B each

    const int total = n_chunks[0];
    const int q  = total >> 3;
    const int r8 = total & 7;

    __shared__ float t_lds[CHUNK][DIM];
    __shared__ float h_lds[CHUNK][DIM];
    __shared__ float red[4][CHUNK];
    __shared__ float htr[CHUNK];
    __shared__ float r2_red[4];

    for (int k = blockIdx.x; k < total; k += MGRID) {
        // bijective XCD swizzle over [0,total)
        const int x   = k & 7;
        const int jj  = k >> 3;
        const int cid = (x < r8 ? x * (q + 1) : r8 * (q + 1) + (x - r8) * q) + jj;

        const int4 ci    = chunk_info[cid];
        const int  rel   = ci.x;
        const int  start = ci.y;
        const int  e_cnt = ci.z;

        // ---- S: stage t, h (16 threads/element, 2 float4 each) ----
        float4 t0 = make_float4(0.f,0.f,0.f,0.f), t1 = t0, g0 = t0, g1 = t0;
        if (eg < e_cnt) {
            const int4 qd = quad[start + eg];
            const float* hp = ent_w + (size_t)qd.x * DIM + sub * 8;
            const float* tp = ent_w + (size_t)qd.y * DIM + sub * 8;
            g0 = *(const float4*)hp;  g1 = *(const float4*)(hp + 4);
            t0 = *(const float4*)tp;  t1 = *(const float4*)(tp + 4);
        }
        *(float4*)&t_lds[eg][sub * 8]     = t0;
        *(float4*)&t_lds[eg][sub * 8 + 4] = t1;
        *(float4*)&h_lds[eg][sub * 8]     = g0;
        *(float4*)&h_lds[eg][sub * 8 + 4] = g1;

        float htp = dot4(t0,t0) + dot4(t1,t1) + dot4(g0,g0) + dot4(g1,g1);
        #pragma unroll
        for (int off = 8; off >= 1; off >>= 1) htp += __shfl_xor(htp, off);
        if (sub == 0) htr[eg] = htp;
        __syncthreads();                                   // B1

        // ---- C: compute (R streamed in two 8-row halves) ----
        const float4* Rb = (const float4*)(rel_w + (size_t)rel * (DIM * DIM)
                                                 + (size_t)rbase * DIM) + c4;
        float acc[CHUNK];
        #pragma unroll
        for (int e = 0; e < CHUNK; ++e) acc[e] = 0.f;
        float r2 = 0.f;

        #pragma unroll 1
        for (int half = 0; half < 2; ++half) {
            float4 rA[8];
            #pragma unroll
            for (int p = 0; p < 8; ++p)
                rA[p] = Rb[(8 * half + p) * (DIM / 4)];
            #pragma unroll
            for (int p = 0; p < 8; ++p) r2 += dot4(rA[p], rA[p]);
            #pragma unroll
            for (int e = 0; e < CHUNK; ++e) {
                const float4 te = *(const float4*)&t_lds[e][c4 * 4];
                const float4 h0 = *(const float4*)&h_lds[e][rbase + 8 * half];
                const float4 h1 = *(const float4*)&h_lds[e][rbase + 8 * half + 4];
                acc[e] += h0.x * dot4(rA[0], te) + h0.y * dot4(rA[1], te)
                        + h0.z * dot4(rA[2], te) + h0.w * dot4(rA[3], te)
                        + h1.x * dot4(rA[4], te) + h1.y * dot4(rA[5], te)
                        + h1.z * dot4(rA[6], te) + h1.w * dot4(rA[7], te);
            }
        }

        // reductions (slot-invariant trees -> scores bit-stable)
        #pragma unroll
        for (int off = 32; off >= 1; off >>= 1) r2 += __shfl_xor(r2, off);
        if (l == 0) r2_red[w] = r2;

        #pragma unroll
        for (int e = 0; e < CHUNK; ++e) {
            float v = acc[e];
            #pragma unroll
            for (int off = 32; off >= 1; off >>= 1) v += __shfl_xor(v, off);
            if (l == 0) red[w][e] = v;
        }

        // wave 0 pre-reads htr (stable since B1; next write is after B2)
        float hte = 0.f;
        if (w == 0 && l < CHUNK) hte = htr[l];
        __syncthreads();                                   // B2

        // ---- T: wave-0 tail (shfl-only; no extra barrier) ----
        if (w == 0) {
            float dd = 0.f;
            if (l < e_cnt) {
                const float s = red[0][l] + red[1][l] + red[2][l] + red[3][l];
                const int4 qd = quad[start + l];
                scores_out[qd.z] = s;
                const float d = s - __int_as_float(qd.w);
                dd = d * d;
            } else {
                hte = 0.f;
            }
            #pragma unroll
            for (int off = 32; off >= 1; off >>= 1) {
                dd  += __shfl_down(dd, off);
                hte += __shfl_down(hte, off);
            }
            if (l == 0) {
                const float r2t = r2_red[0] + r2_red[1] + r2_red[2] + r2_red[3];
                chunk_out[cid] = make_float4(dd, hte, (float)e_cnt * r2t, 0.f);
            }
        }
        // next iteration's B1 orders wave0's red/r2_red reads vs new writes
    }
}

// ---------- K4: final — fixed-order reduction over [0,total) -> loss ----------
__global__ void __launch_bounds__(256) final_kernel(
    const float4* __restrict__ chunk_out,
    const int*    __restrict__ n_chunks,
    float*        __restrict__ loss_out)
{
    const int tid = threadIdx.x;
    const int total = n_chunks[0];
    float err = 0.f, ht = 0.f, r2 = 0.f;
    for (int i = tid; i < total; i += 256) {
        const float4 c = chunk_out[i];
        err += c.x; ht += c.y; r2 += c.z;
    }
    __shared__ float re[4], rh[4], rr2[4];
    #pragma unroll
    for (int off = 32; off >= 1; off >>= 1) {
        err += __shfl_down(err, off);
        ht  += __shfl_down(ht, off);
        r2  += __shfl_down(r2, off);
    }
    if ((tid & 63) == 0) { const int v = tid >> 6; re[v] = err; rh[v] = ht; rr2[v] = r2; }
    __syncthreads();
    if (tid == 0) {
        err = re[0] + re[1] + re[2] + re[3];
        ht  = rh[0] + rh[1] + rh[2] + rh[3];
        r2  = rr2[0] + rr2[1] + rr2[2] + rr2[3];
        const float mse   = err / (float)BATCH;
        const float norms = (ht / ((float)BATCH * DIM)
                           + r2 / ((float)BATCH * (float)(DIM * DIM))) / 3.0f;
        loss_out[0] = mse + ALPHA * norms;
    }
}

extern "C" void kernel_launch(void* const* d_in, const int* in_sizes, int n_in,
                              void* d_out, int out_size, void* d_ws, size_t ws_size,
                              hipStream_t stream) {
    const int*   h_idx  = (const int*)d_in[0];
    const int*   r_idx  = (const int*)d_in[1];
    const int*   t_idx  = (const int*)d_in[2];
    const float* labels = (const float*)d_in[3];
    const float* ent_w  = (const float*)d_in[4];
    const float* rel_w  = (const float*)d_in[5];

    float* out = (float*)d_out;   // [0]=loss, [1..BATCH]=scores

    // workspace layout (~440 KB)
    char* ws = (char*)d_ws;
    int4*   quad       = (int4*)ws;             ws += BATCH * sizeof(int4);        // 256K
    int*    partialT   = (int*)ws;              ws += 512 * NHB * sizeof(int);     // 128K
    int4*   chunk_info = (int4*)ws;             ws += MAXCHUNKS * sizeof(int4);    // ~24K
    float4* chunk_out  = (float4*)ws;           ws += MAXCHUNKS * sizeof(float4);  // ~24K
    int*    n_chunks   = (int*)ws;

    hist_kernel<<<NHB, 256, 0, stream>>>(r_idx, partialT);
    scatter_kernel<<<NHB, 256, 0, stream>>>(r_idx, h_idx, t_idx, labels,
                                            partialT, quad, chunk_info, n_chunks);
    rescal_main_kernel<<<MGRID, 256, 0, stream>>>(
        chunk_info, quad, ent_w, rel_w, n_chunks, out + 1, chunk_out);
    final_kernel<<<1, 256, 0, stream>>>(chunk_out, n_chunks, out);
}

// Round 16
// 46.909 us; speedup vs baseline: 1.2136x; 1.2093x over previous
//
#include <hip/hip_runtime.h>

#define DIM       128
#define BATCH     16384
#define RELN      500
#define ALPHA     0.001f
#define CHUNK     8
#define MAXCHUNKS (BATCH / CHUNK + RELN)   // 2548 chunk slots (padded)
#define PBLK      32                       // prep blocks (512 threads each)

__device__ __forceinline__ float dot4(float4 a, float4 b) {
    return a.x * b.x + a.y * b.y + a.z * b.z + a.w * b.w;
}

// ---------- K1: fused prep — hist + scan + scatter + chunk_info, LDS only ----------
__global__ void __launch_bounds__(512) prep_kernel(
    const int*   __restrict__ r_idx,
    const int*   __restrict__ h_idx,
    const int*   __restrict__ t_idx,
    const float* __restrict__ labels,
    int4*        __restrict__ quad,        // [BATCH] (h, t, b, label_bits)
    int4*        __restrict__ chunk_info)  // [MAXCHUNKS] (rel, start, e_cnt, 0)
{
    __shared__ int cntAll[512];
    __shared__ int cntPre[512];
    __shared__ int sc[512];
    __shared__ int exclA[512];
    const int tid     = threadIdx.x;
    const int bid     = blockIdx.x;
    const int myStart = bid * 512;

    cntAll[tid] = 0;
    cntPre[tid] = 0;
    __syncthreads();

    // full + prefix histograms (LDS atomics; counts are order-invariant)
    #pragma unroll 4
    for (int k = 0; k < BATCH / 512; ++k) {
        const int i = tid + k * 512;           // coalesced
        const int r = r_idx[i];
        atomicAdd(&cntAll[r], 1);
        if (i < myStart) atomicAdd(&cntPre[r], 1);
    }
    __syncthreads();

    // inclusive scan of cntAll -> excl
    sc[tid] = cntAll[tid];
    __syncthreads();
    for (int d = 1; d < 512; d <<= 1) {
        const int x = (tid >= d) ? sc[tid - d] : 0;
        __syncthreads();
        sc[tid] += x;
        __syncthreads();
    }
    exclA[tid] = sc[tid] - cntAll[tid];
    __syncthreads();

    // scatter own element: pos = excl[r] + (#prior with r) + rank
    {
        const int i = myStart + tid;
        const int r = r_idx[i];
        const int pos = exclA[r] + atomicAdd(&cntPre[r], 1);
        quad[pos] = make_int4(h_idx[i], t_idx[i], i, __float_as_int(labels[i]));
    }

    // block 0: chunk list (+ zero tail). Uniform branch; internal barriers OK.
    if (bid == 0) {
        const int cnt = cntAll[tid];
        const int nc  = (tid < RELN) ? (cnt + CHUNK - 1) / CHUNK : 0;
        __syncthreads();
        sc[tid] = nc;
        __syncthreads();
        for (int d = 1; d < 512; d <<= 1) {
            const int x = (tid >= d) ? sc[tid - d] : 0;
            __syncthreads();
            sc[tid] += x;
            __syncthreads();
        }
        const int cbase = sc[tid] - nc;
        const int total = sc[511];
        for (int i = 0; i < nc; ++i)
            chunk_info[cbase + i] = make_int4(
                tid, exclA[tid] + i * CHUNK, min(CHUNK, cnt - i * CHUNK), 0);
        for (int p = total + tid; p < MAXCHUNKS; p += 512)
            chunk_info[p] = make_int4(0, 0, 0, 0);
    }
}

// ---------- K2: main — one block per chunk of 8; R streamed in 4-row groups ----------
__global__ void __launch_bounds__(256) rescal_main_kernel(
    const int4*  __restrict__ chunk_info,
    const int4*  __restrict__ quad,
    const float* __restrict__ ent_w,
    const float* __restrict__ rel_w,
    float*       __restrict__ scores_out,   // d_out + 1
    float4*      __restrict__ chunk_out)    // [MAXCHUNKS] (errS, htS, cnt*r2, 0)
{
    // bijective XCD swizzle: consecutive cids (same relation) share an XCD L2
    const int bid = blockIdx.x;
    const int xcd = bid & 7;
    const int j   = bid >> 3;
    const int q   = MAXCHUNKS / 8;
    const int r_  = MAXCHUNKS % 8;
    const int cid = (xcd < r_ ? xcd * (q + 1) : r_ * (q + 1) + (xcd - r_) * q) + j;

    const int tid = threadIdx.x;

    const int4 ci    = chunk_info[cid];
    const int  rel   = ci.x;
    const int  start = ci.y;
    const int  e_cnt = ci.z;
    if (e_cnt == 0) {                        // padded slot: zero for final's pass
        if (tid == 0) chunk_out[cid] = make_float4(0.f, 0.f, 0.f, 0.f);
        return;
    }

    const int w   = tid >> 6;
    const int l   = tid & 63;
    const int hi  = l >> 5;
    const int c4  = l & 31;
    const int rbase = 32 * w + 16 * hi;

    __shared__ float t_lds[CHUNK][DIM];
    __shared__ float h_lds[CHUNK][DIM];
    __shared__ float red[4][CHUNK];
    __shared__ float ht_red[CHUNK];
    __shared__ float d2s[CHUNK];
    __shared__ float r2_red[4];

    // stage t, h (32 threads per element, 1 float4 each)
    const int eg   = tid >> 5;
    const int col4 = tid & 31;
    float4 tv4 = make_float4(0.f, 0.f, 0.f, 0.f);
    float4 hv4 = tv4;
    if (eg < e_cnt) {
        const int4 qd = quad[start + eg];
        hv4 = *(const float4*)(ent_w + (size_t)qd.x * DIM + col4 * 4);
        tv4 = *(const float4*)(ent_w + (size_t)qd.y * DIM + col4 * 4);
    }
    *(float4*)&t_lds[eg][col4 * 4] = tv4;
    *(float4*)&h_lds[eg][col4 * 4] = hv4;

    float htp = dot4(tv4, tv4) + dot4(hv4, hv4);
    #pragma unroll
    for (int off = 16; off >= 1; off >>= 1) htp += __shfl_xor(htp, off);
    if ((tid & 31) == 0) ht_red[eg] = htp;
    __syncthreads();

    // t fragments to registers (b128, conflict-free)
    float4 t4[CHUNK];
    #pragma unroll
    for (int e = 0; e < CHUNK; ++e)
        t4[e] = *(const float4*)&t_lds[e][c4 * 4];

    // stream R in 4-row groups (only 16 R-regs live)
    const float4* Rb = (const float4*)(rel_w + (size_t)rel * (DIM * DIM)
                                             + (size_t)rbase * DIM) + c4;
    float acc[CHUNK];
    #pragma unroll
    for (int e = 0; e < CHUNK; ++e) acc[e] = 0.f;
    float r2 = 0.f;

    #pragma unroll 1
    for (int pg = 0; pg < 4; ++pg) {
        const float4 r0 = Rb[(4 * pg + 0) * (DIM / 4)];
        const float4 r1 = Rb[(4 * pg + 1) * (DIM / 4)];
        const float4 rq = Rb[(4 * pg + 2) * (DIM / 4)];
        const float4 r3 = Rb[(4 * pg + 3) * (DIM / 4)];
        r2 += dot4(r0, r0) + dot4(r1, r1) + dot4(rq, rq) + dot4(r3, r3);
        #pragma unroll
        for (int e = 0; e < CHUNK; ++e) {
            const float4 h4 = *(const float4*)&h_lds[e][rbase + 4 * pg];
            acc[e] += h4.x * dot4(r0, t4[e]) + h4.y * dot4(r1, t4[e])
                    + h4.z * dot4(rq, t4[e]) + h4.w * dot4(r3, t4[e]);
        }
    }

    // reductions (slot-invariant trees -> scores bit-stable)
    #pragma unroll
    for (int off = 32; off >= 1; off >>= 1) r2 += __shfl_xor(r2, off);
    if (l == 0) r2_red[w] = r2;

    #pragma unroll
    for (int e = 0; e < CHUNK; ++e) {
        float v = acc[e];
        #pragma unroll
        for (int off = 32; off >= 1; off >>= 1) v += __shfl_xor(v, off);
        if (l == 0) red[w][e] = v;
    }
    __syncthreads();

    if (tid < e_cnt) {
        const float s  = red[0][tid] + red[1][tid] + red[2][tid] + red[3][tid];
        const int4 qd  = quad[start + tid];          // L1-hot reread
        scores_out[qd.z] = s;
        const float d  = s - __int_as_float(qd.w);
        d2s[tid] = d * d;
    }
    __syncthreads();

    if (tid == 0) {
        float err = 0.f, ht = 0.f;
        for (int e = 0; e < e_cnt; ++e) { err += d2s[e]; ht += ht_red[e]; }
        const float r2t = r2_red[0] + r2_red[1] + r2_red[2] + r2_red[3];
        chunk_out[cid] = make_float4(err, ht, (float)e_cnt * r2t, 0.f);
    }
}

// ---------- K3: final — fixed-order reduction over full chunk_out -> loss ----------
__global__ void __launch_bounds__(256) final_kernel(
    const float4* __restrict__ chunk_out,
    float*        __restrict__ loss_out)
{
    const int tid = threadIdx.x;
    float err = 0.f, ht = 0.f, r2 = 0.f;
    for (int i = tid; i < MAXCHUNKS; i += 256) {
        const float4 c = chunk_out[i];
        err += c.x; ht += c.y; r2 += c.z;
    }
    __shared__ float re[4], rh[4], rr2[4];
    #pragma unroll
    for (int off = 32; off >= 1; off >>= 1) {
        err += __shfl_down(err, off);
        ht  += __shfl_down(ht, off);
        r2  += __shfl_down(r2, off);
    }
    if ((tid & 63) == 0) { const int v = tid >> 6; re[v] = err; rh[v] = ht; rr2[v] = r2; }
    __syncthreads();
    if (tid == 0) {
        err = re[0] + re[1] + re[2] + re[3];
        ht  = rh[0] + rh[1] + rh[2] + rh[3];
        r2  = rr2[0] + rr2[1] + rr2[2] + rr2[3];
        const float mse   = err / (float)BATCH;
        const float norms = (ht / ((float)BATCH * DIM)
                           + r2 / ((float)BATCH * (float)(DIM * DIM))) / 3.0f;
        loss_out[0] = mse + ALPHA * norms;
    }
}

extern "C" void kernel_launch(void* const* d_in, const int* in_sizes, int n_in,
                              void* d_out, int out_size, void* d_ws, size_t ws_size,
                              hipStream_t stream) {
    const int*   h_idx  = (const int*)d_in[0];
    const int*   r_idx  = (const int*)d_in[1];
    const int*   t_idx  = (const int*)d_in[2];
    const float* labels = (const float*)d_in[3];
    const float* ent_w  = (const float*)d_in[4];
    const float* rel_w  = (const float*)d_in[5];

    float* out = (float*)d_out;   // [0]=loss, [1..BATCH]=scores

    // workspace layout (~340 KB)
    char* ws = (char*)d_ws;
    int4*   quad       = (int4*)ws;             ws += BATCH * sizeof(int4);        // 256K
    int4*   chunk_info = (int4*)ws;             ws += MAXCHUNKS * sizeof(int4);    // ~41K
    float4* chunk_out  = (float4*)ws;           // ~41K

    prep_kernel<<<PBLK, 512, 0, stream>>>(r_idx, h_idx, t_idx, labels,
                                          quad, chunk_info);
    rescal_main_kernel<<<MAXCHUNKS, 256, 0, stream>>>(
        chunk_info, quad, ent_w, rel_w, out + 1, chunk_out);
    final_kernel<<<1, 256, 0, stream>>>(chunk_out, out);
}

// Round 17
// 29.969 us; speedup vs baseline: 1.8997x; 1.5653x over previous
//
#include <hip/hip_runtime.h>

#define DIM    128
#define BATCH  16384
#define RELN   500
#define ALPHA  0.001f
#define PBLK   32                       // prep blocks (512 threads each)
#define EB     32                       // elements per batch in main kernel

typedef __bf16 bf16x8 __attribute__((ext_vector_type(8)));
typedef float  f32x4  __attribute__((ext_vector_type(4)));

__device__ __forceinline__ float dot4(float4 a, float4 b) {
    return a.x * b.x + a.y * b.y + a.z * b.z + a.w * b.w;
}

struct bfx4 { __bf16 a, b, c, d; };
__device__ __forceinline__ bfx4 cvt4(float4 v) {
    bfx4 r; r.a = (__bf16)v.x; r.b = (__bf16)v.y; r.c = (__bf16)v.z; r.d = (__bf16)v.w;
    return r;
}

// ---------- K1: fused prep — hist + scan + scatter + rel_info, LDS only ----------
__global__ void __launch_bounds__(512) prep_kernel(
    const int*   __restrict__ r_idx,
    const int*   __restrict__ h_idx,
    const int*   __restrict__ t_idx,
    const float* __restrict__ labels,
    int4*        __restrict__ quad,      // [BATCH] (h, t, b, label_bits)
    int2*        __restrict__ rel_info)  // [RELN] (start, count)
{
    __shared__ int cntAll[512];
    __shared__ int cntPre[512];
    __shared__ int sc[512];
    __shared__ int exclA[512];
    const int tid     = threadIdx.x;
    const int bid     = blockIdx.x;
    const int myStart = bid * 512;

    cntAll[tid] = 0;
    cntPre[tid] = 0;
    __syncthreads();

    #pragma unroll 4
    for (int k = 0; k < BATCH / 512; ++k) {
        const int i = tid + k * 512;
        const int r = r_idx[i];
        atomicAdd(&cntAll[r], 1);
        if (i < myStart) atomicAdd(&cntPre[r], 1);
    }
    __syncthreads();

    sc[tid] = cntAll[tid];
    __syncthreads();
    for (int d = 1; d < 512; d <<= 1) {
        const int x = (tid >= d) ? sc[tid - d] : 0;
        __syncthreads();
        sc[tid] += x;
        __syncthreads();
    }
    exclA[tid] = sc[tid] - cntAll[tid];
    __syncthreads();

    {
        const int i = myStart + tid;
        const int r = r_idx[i];
        const int pos = exclA[r] + atomicAdd(&cntPre[r], 1);
        quad[pos] = make_int4(h_idx[i], t_idx[i], i, __float_as_int(labels[i]));
    }

    if (bid == 0 && tid < RELN)
        rel_info[tid] = make_int2(exclA[tid], cntAll[tid]);
}

// ---------- K2: main — one block per relation; bf16 MFMA over element batches ----------
// Block stages R (64KB fp32 -> bf16 LDS, r2 in fp32) once, then loops batches
// of <=32 elements: stage T(bf16)/H(f32)/idx/label, MFMA 16x16x32 tiles
// (A = R rows, B = T columns), epilogue s_j = sum_rows H[row][j]*Rt[row][j].
// Scores are per-element exact and order-invariant (MFMA K-order fixed).
// Padded LDS rows (136 bf16 / 132 f32) -> <=2-way bank conflicts (free).
__global__ void __launch_bounds__(256) rescal_mfma_kernel(
    const int2*  __restrict__ rel_info,
    const int4*  __restrict__ quad,
    const float* __restrict__ ent_w,
    const float* __restrict__ rel_w,
    float*       __restrict__ scores_out,  // d_out + 1
    float4*      __restrict__ rel_out)     // [RELN] (errS, htS, n*r2, 0)
{
    const int rel = blockIdx.x;
    const int tid = threadIdx.x;
    const int w   = tid >> 6;
    const int l   = tid & 63;

    const int2 ri   = rel_info[rel];
    const int start = ri.x;
    const int n     = ri.y;

    __shared__ __align__(16) __bf16 Rbf[DIM][136];   // 34816 B
    __shared__ __align__(16) __bf16 Tbf[EB][136];    //  8704 B
    __shared__ __align__(16) float  Hld[EB][132];    // 16896 B
    __shared__ float s_red[4][EB];
    __shared__ int   bidx[EB];
    __shared__ float blab[EB];
    __shared__ float rw[4], hw[4], dw[4];

    if (n == 0) {
        if (tid == 0) rel_out[rel] = make_float4(0.f, 0.f, 0.f, 0.f);
        return;
    }

    // ---- stage R: 4096 float4 coalesced, fp32 r2, bf16 into padded LDS ----
    const float4* Rg = (const float4*)(rel_w + (size_t)rel * (DIM * DIM));
    float r2 = 0.f;
    #pragma unroll
    for (int it = 0; it < 16; ++it) {
        const int f   = it * 256 + tid;        // float4 index
        const float4 v = Rg[f];
        r2 += dot4(v, v);
        const int row = f >> 5;                // 32 float4 per row
        const int c4  = f & 31;
        *(bfx4*)&Rbf[row][c4 * 4] = cvt4(v);
    }

    float ht_run = 0.f;      // part==0 threads accumulate per-elem h2+t2
    float d2_run = 0.f;      // wave0 lanes<EB accumulate (s-label)^2

    const int elem = tid >> 3;     // 0..31 (8 threads per element)
    const int part = tid & 7;

    const int nb = (n + EB - 1) / EB;
    for (int bt = 0; bt < nb; ++bt) {
        const int base = start + bt * EB;
        const int nb_e = min(EB, n - bt * EB);

        // ---- stage T/H for this batch ----
        if (elem < nb_e) {
            const int4 qd = quad[base + elem];
            const float4* hp = (const float4*)(ent_w + (size_t)qd.x * DIM) + part * 4;
            const float4* tp = (const float4*)(ent_w + (size_t)qd.y * DIM) + part * 4;
            float htp = 0.f;
            #pragma unroll
            for (int j = 0; j < 4; ++j) {
                const float4 tv = tp[j];
                const float4 hv = hp[j];
                htp += dot4(tv, tv) + dot4(hv, hv);
                *(bfx4*)&Tbf[elem][part * 16 + j * 4]   = cvt4(tv);
                *(float4*)&Hld[elem][part * 16 + j * 4] = hv;
            }
            #pragma unroll
            for (int off = 4; off >= 1; off >>= 1) htp += __shfl_xor(htp, off);
            if (part == 0) {
                bidx[elem] = qd.z;
                blab[elem] = __int_as_float(qd.w);
                ht_run += htp;
            }
        }
        __syncthreads();                                    // B1

        // ---- compute: wave w owns row-tiles {w, w+4} ----
        float p0 = 0.f, p1 = 0.f;
        #pragma unroll
        for (int ct = 0; ct < 2; ++ct) {
            if (ct * 16 >= nb_e) break;                     // uniform
            #pragma unroll
            for (int rti = 0; rti < 2; ++rti) {
                const int rt = w + rti * 4;
                f32x4 c = {0.f, 0.f, 0.f, 0.f};
                #pragma unroll
                for (int s = 0; s < 4; ++s) {
                    const bf16x8 a = *(const bf16x8*)
                        &Rbf[rt * 16 + (l & 15)][s * 32 + (l >> 4) * 8];
                    const bf16x8 b = *(const bf16x8*)
                        &Tbf[ct * 16 + (l & 15)][s * 32 + (l >> 4) * 8];
                    c = __builtin_amdgcn_mfma_f32_16x16x32_bf16(a, b, c, 0, 0, 0);
                }
                // epilogue: col j = ct*16 + (l&15); rows rt*16 + 4*(l>>4) + i
                const int jcol = ct * 16 + (l & 15);
                const int rw0  = rt * 16 + 4 * (l >> 4);
                float pp = Hld[jcol][rw0 + 0] * c[0]
                         + Hld[jcol][rw0 + 1] * c[1]
                         + Hld[jcol][rw0 + 2] * c[2]
                         + Hld[jcol][rw0 + 3] * c[3];
                if (ct == 0) p0 += pp; else p1 += pp;
            }
        }
        p0 += __shfl_xor(p0, 16); p0 += __shfl_xor(p0, 32);
        p1 += __shfl_xor(p1, 16); p1 += __shfl_xor(p1, 32);
        if (l < 16) { s_red[w][l] = p0; s_red[w][16 + l] = p1; }

        // wave0 pre-reads idx/label (stable since B1; rewritten only after B2)
        int   rb = 0; float lb = 0.f;
        if (w == 0 && l < EB) { rb = bidx[l]; lb = blab[l]; }
        __syncthreads();                                    // B2

        // ---- wave-0 epilogue: full scores + d^2 accumulation ----
        if (w == 0 && l < nb_e) {
            const float s = s_red[0][l] + s_red[1][l] + s_red[2][l] + s_red[3][l];
            scores_out[rb] = s;
            const float d = s - lb;
            d2_run += d * d;
        }
        // next staging overwrites Tbf/Hld/bidx: all compute reads were pre-B2;
        // s_red rewritten only after next B1.
    }

    // ---- block reduction of r2 / ht / d2 ----
    float v0 = r2, v1 = ht_run, v2 = d2_run;
    #pragma unroll
    for (int off = 32; off >= 1; off >>= 1) {
        v0 += __shfl_xor(v0, off);
        v1 += __shfl_xor(v1, off);
        v2 += __shfl_xor(v2, off);
    }
    if (l == 0) { rw[w] = v0; hw[w] = v1; dw[w] = v2; }
    __syncthreads();
    if (tid == 0) {
        const float r2t = rw[0] + rw[1] + rw[2] + rw[3];
        const float htt = hw[0] + hw[1] + hw[2] + hw[3];
        const float d2t = dw[0] + dw[1] + dw[2] + dw[3];
        rel_out[rel] = make_float4(d2t, htt, (float)n * r2t, 0.f);
    }
}

// ---------- K3: final — fixed-order reduction over rel_out -> loss ----------
__global__ void __launch_bounds__(256) final_kernel(
    const float4* __restrict__ rel_out,
    float*        __restrict__ loss_out)
{
    const int tid = threadIdx.x;
    float err = 0.f, ht = 0.f, r2 = 0.f;
    for (int i = tid; i < RELN; i += 256) {
        const float4 c = rel_out[i];
        err += c.x; ht += c.y; r2 += c.z;
    }
    __shared__ float re[4], rh[4], rr2[4];
    #pragma unroll
    for (int off = 32; off >= 1; off >>= 1) {
        err += __shfl_down(err, off);
        ht  += __shfl_down(ht, off);
        r2  += __shfl_down(r2, off);
    }
    if ((tid & 63) == 0) { const int v = tid >> 6; re[v] = err; rh[v] = ht; rr2[v] = r2; }
    __syncthreads();
    if (tid == 0) {
        err = re[0] + re[1] + re[2] + re[3];
        ht  = rh[0] + rh[1] + rh[2] + rh[3];
        r2  = rr2[0] + rr2[1] + rr2[2] + rr2[3];
        const float mse   = err / (float)BATCH;
        const float norms = (ht / ((float)BATCH * DIM)
                           + r2 / ((float)BATCH * (float)(DIM * DIM))) / 3.0f;
        loss_out[0] = mse + ALPHA * norms;
    }
}

extern "C" void kernel_launch(void* const* d_in, const int* in_sizes, int n_in,
                              void* d_out, int out_size, void* d_ws, size_t ws_size,
                              hipStream_t stream) {
    const int*   h_idx  = (const int*)d_in[0];
    const int*   r_idx  = (const int*)d_in[1];
    const int*   t_idx  = (const int*)d_in[2];
    const float* labels = (const float*)d_in[3];
    const float* ent_w  = (const float*)d_in[4];
    const float* rel_w  = (const float*)d_in[5];

    float* out = (float*)d_out;   // [0]=loss, [1..BATCH]=scores

    // workspace layout (~270 KB)
    char* ws = (char*)d_ws;
    int4*   quad     = (int4*)ws;               ws += BATCH * sizeof(int4);   // 256K
    int2*   rel_info = (int2*)ws;               ws += 512 * sizeof(int2);     // 4K
    float4* rel_out  = (float4*)ws;             // 8K

    prep_kernel<<<PBLK, 512, 0, stream>>>(r_idx, h_idx, t_idx, labels,
                                          quad, rel_info);
    rescal_mfma_kernel<<<RELN, 256, 0, stream>>>(
        rel_info, quad, ent_w, rel_w, out + 1, rel_out);
    final_kernel<<<1, 256, 0, stream>>>(rel_out, out);
}

// Round 18
// 29.887 us; speedup vs baseline: 1.9048x; 1.0027x over previous
//
#include <hip/hip_runtime.h>

#define DIM    128
#define BATCH  16384
#define RELN   500
#define ALPHA  0.001f
#define PBLK   32                       // prep blocks (512 threads each)
#define EB     32                       // elements per batch in main kernel

typedef __bf16 bf16x8 __attribute__((ext_vector_type(8)));
typedef float  f32x4  __attribute__((ext_vector_type(4)));

__device__ __forceinline__ float dot4(float4 a, float4 b) {
    return a.x * b.x + a.y * b.y + a.z * b.z + a.w * b.w;
}

struct bfx4 { __bf16 a, b, c, d; };
__device__ __forceinline__ bfx4 cvt4(float4 v) {
    bfx4 r; r.a = (__bf16)v.x; r.b = (__bf16)v.y; r.c = (__bf16)v.z; r.d = (__bf16)v.w;
    return r;
}

// ---------- K1: fused prep — hist + scan + scatter + rel_info, LDS only ----------
__global__ void __launch_bounds__(512) prep_kernel(
    const int*   __restrict__ r_idx,
    const int*   __restrict__ h_idx,
    const int*   __restrict__ t_idx,
    const float* __restrict__ labels,
    int4*        __restrict__ quad,      // [BATCH] (h, t, b, label_bits)
    int2*        __restrict__ rel_info)  // [RELN] (start, count)
{
    __shared__ int cntAll[512];
    __shared__ int cntPre[512];
    __shared__ int sc[512];
    __shared__ int exclA[512];
    const int tid     = threadIdx.x;
    const int bid     = blockIdx.x;
    const int myStart = bid * 512;

    cntAll[tid] = 0;
    cntPre[tid] = 0;
    __syncthreads();

    #pragma unroll 4
    for (int k = 0; k < BATCH / 512; ++k) {
        const int i = tid + k * 512;
        const int r = r_idx[i];
        atomicAdd(&cntAll[r], 1);
        if (i < myStart) atomicAdd(&cntPre[r], 1);
    }
    __syncthreads();

    sc[tid] = cntAll[tid];
    __syncthreads();
    for (int d = 1; d < 512; d <<= 1) {
        const int x = (tid >= d) ? sc[tid - d] : 0;
        __syncthreads();
        sc[tid] += x;
        __syncthreads();
    }
    exclA[tid] = sc[tid] - cntAll[tid];
    __syncthreads();

    {
        const int i = myStart + tid;
        const int r = r_idx[i];
        const int pos = exclA[r] + atomicAdd(&cntPre[r], 1);
        quad[pos] = make_int4(h_idx[i], t_idx[i], i, __float_as_int(labels[i]));
    }

    if (bid == 0 && tid < RELN)
        rel_info[tid] = make_int2(exclA[tid], cntAll[tid]);
}

// ---------- K2: main — one 512-thread block per relation; bf16 MFMA ----------
// 8 waves; wave w owns row-tile w (16 rows). R staged once (bf16, r2 fp32);
// per 32-elem batch: stage T/H (bf16, 16 thr/elem), MFMA 16x16x32 over 2
// col-tiles, epilogue s_j = sum_rows h*Rt. LDS 53.6KB -> 3 blocks/CU
// (24 waves/CU) and all 500 blocks co-resident. Deterministic: fixed MFMA
// K-order, slot-invariant reductions.
__global__ void __launch_bounds__(512) rescal_mfma_kernel(
    const int2*  __restrict__ rel_info,
    const int4*  __restrict__ quad,
    const float* __restrict__ ent_w,
    const float* __restrict__ rel_w,
    float*       __restrict__ scores_out,  // d_out + 1
    float4*      __restrict__ rel_out)     // [RELN] (errS, htS, n*r2, 0)
{
    const int rel = blockIdx.x;
    const int tid = threadIdx.x;
    const int w   = tid >> 6;      // 0..7
    const int l   = tid & 63;

    const int2 ri   = rel_info[rel];
    const int start = ri.x;
    const int n     = ri.y;

    __shared__ __align__(16) __bf16 Rbf[DIM][136];   // 34816 B
    __shared__ __align__(16) __bf16 Tbf[EB][136];    //  8704 B
    __shared__ __align__(16) __bf16 Hbf[EB][136];    //  8704 B
    __shared__ float s_red[8][EB];                   //  1024 B
    __shared__ int   bidx[EB];
    __shared__ float blab[EB];
    __shared__ float rw_[8], hw_[8], dw_[8];

    if (n == 0) {
        if (tid == 0) rel_out[rel] = make_float4(0.f, 0.f, 0.f, 0.f);
        return;
    }

    // ---- stage R: 4096 float4 coalesced, fp32 r2, bf16 into padded LDS ----
    const float4* Rg = (const float4*)(rel_w + (size_t)rel * (DIM * DIM));
    float r2 = 0.f;
    #pragma unroll
    for (int it = 0; it < 8; ++it) {
        const int f    = it * 512 + tid;       // float4 index
        const float4 v = Rg[f];
        r2 += dot4(v, v);
        const int row = f >> 5;                // 32 float4 per row
        const int c4  = f & 31;
        *(bfx4*)&Rbf[row][c4 * 4] = cvt4(v);
    }

    float ht_run = 0.f;      // part==0 threads accumulate per-elem h2+t2
    float d2_run = 0.f;      // wave0 lanes<EB accumulate (s-label)^2

    const int elem = tid >> 4;     // 0..31 (16 threads per element)
    const int part = tid & 15;     // 2 float4 each

    const int nb = (n + EB - 1) / EB;
    for (int bt = 0; bt < nb; ++bt) {
        const int base = start + bt * EB;
        const int nb_e = min(EB, n - bt * EB);

        // ---- stage T/H for this batch ----
        if (elem < nb_e) {
            const int4 qd = quad[base + elem];
            const float4* hp = (const float4*)(ent_w + (size_t)qd.x * DIM) + part * 2;
            const float4* tp = (const float4*)(ent_w + (size_t)qd.y * DIM) + part * 2;
            float htp = 0.f;
            #pragma unroll
            for (int j = 0; j < 2; ++j) {
                const float4 tv = tp[j];
                const float4 hv = hp[j];
                htp += dot4(tv, tv) + dot4(hv, hv);
                *(bfx4*)&Tbf[elem][part * 8 + j * 4] = cvt4(tv);
                *(bfx4*)&Hbf[elem][part * 8 + j * 4] = cvt4(hv);
            }
            #pragma unroll
            for (int off = 8; off >= 1; off >>= 1) htp += __shfl_xor(htp, off);
            if (part == 0) {
                bidx[elem] = qd.z;
                blab[elem] = __int_as_float(qd.w);
                ht_run += htp;
            }
        }
        __syncthreads();                                    // B1

        // ---- compute: wave w owns row-tile w (rows 16w..16w+15) ----
        float p0 = 0.f, p1 = 0.f;
        #pragma unroll
        for (int ct = 0; ct < 2; ++ct) {
            if (ct * 16 >= nb_e) break;                     // uniform
            f32x4 c = {0.f, 0.f, 0.f, 0.f};
            #pragma unroll
            for (int s = 0; s < 4; ++s) {
                const bf16x8 a = *(const bf16x8*)
                    &Rbf[w * 16 + (l & 15)][s * 32 + (l >> 4) * 8];
                const bf16x8 b = *(const bf16x8*)
                    &Tbf[ct * 16 + (l & 15)][s * 32 + (l >> 4) * 8];
                c = __builtin_amdgcn_mfma_f32_16x16x32_bf16(a, b, c, 0, 0, 0);
            }
            // epilogue: col j = ct*16 + (l&15); rows w*16 + 4*(l>>4) + i
            const int jcol = ct * 16 + (l & 15);
            const int rw0  = w * 16 + 4 * (l >> 4);
            float pp = (float)Hbf[jcol][rw0 + 0] * c[0]
                     + (float)Hbf[jcol][rw0 + 1] * c[1]
                     + (float)Hbf[jcol][rw0 + 2] * c[2]
                     + (float)Hbf[jcol][rw0 + 3] * c[3];
            if (ct == 0) p0 += pp; else p1 += pp;
        }
        p0 += __shfl_xor(p0, 16); p0 += __shfl_xor(p0, 32);
        p1 += __shfl_xor(p1, 16); p1 += __shfl_xor(p1, 32);
        if (l < 16) { s_red[w][l] = p0; s_red[w][16 + l] = p1; }

        // wave0 pre-reads idx/label (stable since B1; rewritten only after B2)
        int   rb = 0; float lb = 0.f;
        if (w == 0 && l < EB) { rb = bidx[l]; lb = blab[l]; }
        __syncthreads();                                    // B2

        // ---- wave-0 epilogue: full scores + d^2 accumulation ----
        if (w == 0 && l < nb_e) {
            float s = 0.f;
            #pragma unroll
            for (int v = 0; v < 8; ++v) s += s_red[v][l];
            scores_out[rb] = s;
            const float d = s - lb;
            d2_run += d * d;
        }
        // next staging overwrites Tbf/Hbf/bidx: all compute reads were pre-B2;
        // s_red rewritten only after next B1.
    }

    // ---- block reduction of r2 / ht / d2 ----
    float v0 = r2, v1 = ht_run, v2 = d2_run;
    #pragma unroll
    for (int off = 32; off >= 1; off >>= 1) {
        v0 += __shfl_xor(v0, off);
        v1 += __shfl_xor(v1, off);
        v2 += __shfl_xor(v2, off);
    }
    if (l == 0) { rw_[w] = v0; hw_[w] = v1; dw_[w] = v2; }
    __syncthreads();
    if (tid == 0) {
        float r2t = 0.f, htt = 0.f, d2t = 0.f;
        #pragma unroll
        for (int v = 0; v < 8; ++v) { r2t += rw_[v]; htt += hw_[v]; d2t += dw_[v]; }
        rel_out[rel] = make_float4(d2t, htt, (float)n * r2t, 0.f);
    }
}

// ---------- K3: final — fixed-order reduction over rel_out -> loss ----------
__global__ void __launch_bounds__(256) final_kernel(
    const float4* __restrict__ rel_out,
    float*        __restrict__ loss_out)
{
    const int tid = threadIdx.x;
    float err = 0.f, ht = 0.f, r2 = 0.f;
    for (int i = tid; i < RELN; i += 256) {
        const float4 c = rel_out[i];
        err += c.x; ht += c.y; r2 += c.z;
    }
    __shared__ float re[4], rh[4], rr2[4];
    #pragma unroll
    for (int off = 32; off >= 1; off >>= 1) {
        err += __shfl_down(err, off);
        ht  += __shfl_down(ht, off);
        r2  += __shfl_down(r2, off);
    }
    if ((tid & 63) == 0) { const int v = tid >> 6; re[v] = err; rh[v] = ht; rr2[v] = r2; }
    __syncthreads();
    if (tid == 0) {
        err = re[0] + re[1] + re[2] + re[3];
        ht  = rh[0] + rh[1] + rh[2] + rh[3];
        r2  = rr2[0] + rr2[1] + rr2[2] + rr2[3];
        const float mse   = err / (float)BATCH;
        const float norms = (ht / ((float)BATCH * DIM)
                           + r2 / ((float)BATCH * (float)(DIM * DIM))) / 3.0f;
        loss_out[0] = mse + ALPHA * norms;
    }
}

extern "C" void kernel_launch(void* const* d_in, const int* in_sizes, int n_in,
                              void* d_out, int out_size, void* d_ws, size_t ws_size,
                              hipStream_t stream) {
    const int*   h_idx  = (const int*)d_in[0];
    const int*   r_idx  = (const int*)d_in[1];
    const int*   t_idx  = (const int*)d_in[2];
    const float* labels = (const float*)d_in[3];
    const float* ent_w  = (const float*)d_in[4];
    const float* rel_w  = (const float*)d_in[5];

    float* out = (float*)d_out;   // [0]=loss, [1..BATCH]=scores

    // workspace layout (~270 KB)
    char* ws = (char*)d_ws;
    int4*   quad     = (int4*)ws;               ws += BATCH * sizeof(int4);   // 256K
    int2*   rel_info = (int2*)ws;               ws += 512 * sizeof(int2);     // 4K
    float4* rel_out  = (float4*)ws;             // 8K

    prep_kernel<<<PBLK, 512, 0, stream>>>(r_idx, h_idx, t_idx, labels,
                                          quad, rel_info);
    rescal_mfma_kernel<<<RELN, 512, 0, stream>>>(
        rel_info, quad, ent_w, rel_w, out + 1, rel_out);
    final_kernel<<<1, 256, 0, stream>>>(rel_out, out);
}

// Round 19
// 27.123 us; speedup vs baseline: 2.0990x; 1.1019x over previous
//
#include <hip/hip_runtime.h>

#define DIM    128
#define BATCH  16384
#define RELN   500
#define ALPHA  0.001f
#define EB     32                       // elements per batch
#define MAXN   640                      // elist capacity (mean n=33, 15+ sigma)

typedef __bf16 bf16x8 __attribute__((ext_vector_type(8)));
typedef float  f32x4  __attribute__((ext_vector_type(4)));

__device__ __forceinline__ float dot4(float4 a, float4 b) {
    return a.x * b.x + a.y * b.y + a.z * b.z + a.w * b.w;
}

struct bfx4 { __bf16 a, b, c, d; };
__device__ __forceinline__ bfx4 cvt4(float4 v) {
    bfx4 r; r.a = (__bf16)v.x; r.b = (__bf16)v.y; r.c = (__bf16)v.z; r.d = (__bf16)v.w;
    return r;
}

// ---------- K1: main — one 512-thread block per relation; self-bucketing ----------
// Block scans r_idx itself (64KB, L2-broadcast across blocks) -> elist in LDS;
// stages R once (fp32->bf16, r2 fp32); then per 32-elem batch: gather T/H
// (bf16, 16 thr/elem), MFMA 16x16x32 (A=R rows, B=T cols), epilogue
// s_j = sum_rows H*Rt. No prep kernel, no quad round-trip. Deterministic:
// per-element scores exact, fixed MFMA K-order.
__global__ void __launch_bounds__(512) rescal_mfma_kernel(
    const int*   __restrict__ r_idx,
    const int*   __restrict__ h_idx,
    const int*   __restrict__ t_idx,
    const float* __restrict__ labels,
    const float* __restrict__ ent_w,
    const float* __restrict__ rel_w,
    float*       __restrict__ scores_out,  // d_out + 1
    float4*      __restrict__ rel_out)     // [RELN] (errS, htS, n*r2, 0)
{
    const int rel = blockIdx.x;
    const int tid = threadIdx.x;
    const int w   = tid >> 6;      // 0..7
    const int l   = tid & 63;

    __shared__ __align__(16) __bf16 Rbf[DIM][136];   // 34816 B
    __shared__ __align__(16) __bf16 Tbf[EB][136];    //  8704 B
    __shared__ __align__(16) __bf16 Hbf[EB][136];    //  8704 B
    __shared__ int   elist[MAXN];                    //  2560 B
    __shared__ int   ncnt;
    __shared__ float s_red[8][EB];
    __shared__ int   bidx[EB];
    __shared__ float blab[EB];
    __shared__ float rw_[8], hw_[8], dw_[8];

    if (tid == 0) ncnt = 0;

    // ---- stage R: 4096 float4 coalesced, fp32 r2, bf16 into padded LDS ----
    const float4* Rg = (const float4*)(rel_w + (size_t)rel * (DIM * DIM));
    float r2 = 0.f;
    #pragma unroll
    for (int it = 0; it < 8; ++it) {
        const int f    = it * 512 + tid;       // float4 index
        const float4 v = Rg[f];
        r2 += dot4(v, v);
        const int row = f >> 5;                // 32 float4 per row
        const int c4  = f & 31;
        *(bfx4*)&Rbf[row][c4 * 4] = cvt4(v);
    }
    __syncthreads();                           // ncnt=0 visible; Rbf in flight

    // ---- self-bucket: scan r_idx, collect own elements ----
    for (int i = tid; i < BATCH; i += 512) {
        if (r_idx[i] == rel) {
            const int p = atomicAdd(&ncnt, 1);
            if (p < MAXN) elist[p] = i;
        }
    }
    __syncthreads();
    const int n = ncnt;

    if (n == 0) {
        if (tid == 0) rel_out[rel] = make_float4(0.f, 0.f, 0.f, 0.f);
        return;
    }

    float ht_run = 0.f;      // part==0 threads accumulate per-elem h2+t2
    float d2_run = 0.f;      // wave0 lanes<EB accumulate (s-label)^2

    const int elem = tid >> 4;     // 0..31 (16 threads per element)
    const int part = tid & 15;     // 2 float4 each

    const int nb = (n + EB - 1) / EB;
    for (int bt = 0; bt < nb; ++bt) {
        const int nb_e = min(EB, n - bt * EB);

        // ---- stage T/H for this batch (direct gather, no quad) ----
        if (elem < nb_e) {
            const int b  = elist[bt * EB + elem];
            const int hi = h_idx[b];            // same-addr broadcast loads
            const int ti = t_idx[b];
            const float4* hp = (const float4*)(ent_w + (size_t)hi * DIM) + part * 2;
            const float4* tp = (const float4*)(ent_w + (size_t)ti * DIM) + part * 2;
            float htp = 0.f;
            #pragma unroll
            for (int j = 0; j < 2; ++j) {
                const float4 tv = tp[j];
                const float4 hv = hp[j];
                htp += dot4(tv, tv) + dot4(hv, hv);
                *(bfx4*)&Tbf[elem][part * 8 + j * 4] = cvt4(tv);
                *(bfx4*)&Hbf[elem][part * 8 + j * 4] = cvt4(hv);
            }
            #pragma unroll
            for (int off = 8; off >= 1; off >>= 1) htp += __shfl_xor(htp, off);
            if (part == 0) {
                bidx[elem] = b;
                blab[elem] = labels[b];
                ht_run += htp;
            }
        }
        __syncthreads();                                    // B1

        // ---- compute: wave w owns row-tile w (rows 16w..16w+15) ----
        float p0 = 0.f, p1 = 0.f;
        #pragma unroll
        for (int ct = 0; ct < 2; ++ct) {
            if (ct * 16 >= nb_e) break;                     // uniform
            f32x4 c = {0.f, 0.f, 0.f, 0.f};
            #pragma unroll
            for (int s = 0; s < 4; ++s) {
                const bf16x8 a = *(const bf16x8*)
                    &Rbf[w * 16 + (l & 15)][s * 32 + (l >> 4) * 8];
                const bf16x8 b = *(const bf16x8*)
                    &Tbf[ct * 16 + (l & 15)][s * 32 + (l >> 4) * 8];
                c = __builtin_amdgcn_mfma_f32_16x16x32_bf16(a, b, c, 0, 0, 0);
            }
            // epilogue: col j = ct*16 + (l&15); rows w*16 + 4*(l>>4) + i
            const int jcol = ct * 16 + (l & 15);
            const int rw0  = w * 16 + 4 * (l >> 4);
            float pp = (float)Hbf[jcol][rw0 + 0] * c[0]
                     + (float)Hbf[jcol][rw0 + 1] * c[1]
                     + (float)Hbf[jcol][rw0 + 2] * c[2]
                     + (float)Hbf[jcol][rw0 + 3] * c[3];
            if (ct == 0) p0 += pp; else p1 += pp;
        }
        p0 += __shfl_xor(p0, 16); p0 += __shfl_xor(p0, 32);
        p1 += __shfl_xor(p1, 16); p1 += __shfl_xor(p1, 32);
        if (l < 16) { s_red[w][l] = p0; s_red[w][16 + l] = p1; }

        // wave0 pre-reads idx/label (stable since B1; rewritten only after B2)
        int   rb = 0; float lb = 0.f;
        if (w == 0 && l < EB) { rb = bidx[l]; lb = blab[l]; }
        __syncthreads();                                    // B2

        // ---- wave-0 epilogue: full scores + d^2 accumulation ----
        if (w == 0 && l < nb_e) {
            float s = 0.f;
            #pragma unroll
            for (int v = 0; v < 8; ++v) s += s_red[v][l];
            scores_out[rb] = s;
            const float d = s - lb;
            d2_run += d * d;
        }
        // next staging overwrites Tbf/Hbf/bidx: all compute reads were pre-B2;
        // s_red rewritten only after next B1.
    }

    // ---- block reduction of r2 / ht / d2 ----
    float v0 = r2, v1 = ht_run, v2 = d2_run;
    #pragma unroll
    for (int off = 32; off >= 1; off >>= 1) {
        v0 += __shfl_xor(v0, off);
        v1 += __shfl_xor(v1, off);
        v2 += __shfl_xor(v2, off);
    }
    if (l == 0) { rw_[w] = v0; hw_[w] = v1; dw_[w] = v2; }
    __syncthreads();
    if (tid == 0) {
        float r2t = 0.f, htt = 0.f, d2t = 0.f;
        #pragma unroll
        for (int v = 0; v < 8; ++v) { r2t += rw_[v]; htt += hw_[v]; d2t += dw_[v]; }
        rel_out[rel] = make_float4(d2t, htt, (float)n * r2t, 0.f);
    }
}

// ---------- K2: final — fixed-order reduction over rel_out -> loss ----------
__global__ void __launch_bounds__(256) final_kernel(
    const float4* __restrict__ rel_out,
    float*        __restrict__ loss_out)
{
    const int tid = threadIdx.x;
    float err = 0.f, ht = 0.f, r2 = 0.f;
    for (int i = tid; i < RELN; i += 256) {
        const float4 c = rel_out[i];
        err += c.x; ht += c.y; r2 += c.z;
    }
    __shared__ float re[4], rh[4], rr2[4];
    #pragma unroll
    for (int off = 32; off >= 1; off >>= 1) {
        err += __shfl_down(err, off);
        ht  += __shfl_down(ht, off);
        r2  += __shfl_down(r2, off);
    }
    if ((tid & 63) == 0) { const int v = tid >> 6; re[v] = err; rh[v] = ht; rr2[v] = r2; }
    __syncthreads();
    if (tid == 0) {
        err = re[0] + re[1] + re[2] + re[3];
        ht  = rh[0] + rh[1] + rh[2] + rh[3];
        r2  = rr2[0] + rr2[1] + rr2[2] + rr2[3];
        const float mse   = err / (float)BATCH;
        const float norms = (ht / ((float)BATCH * DIM)
                           + r2 / ((float)BATCH * (float)(DIM * DIM))) / 3.0f;
        loss_out[0] = mse + ALPHA * norms;
    }
}

extern "C" void kernel_launch(void* const* d_in, const int* in_sizes, int n_in,
                              void* d_out, int out_size, void* d_ws, size_t ws_size,
                              hipStream_t stream) {
    const int*   h_idx  = (const int*)d_in[0];
    const int*   r_idx  = (const int*)d_in[1];
    const int*   t_idx  = (const int*)d_in[2];
    const float* labels = (const float*)d_in[3];
    const float* ent_w  = (const float*)d_in[4];
    const float* rel_w  = (const float*)d_in[5];

    float* out = (float*)d_out;   // [0]=loss, [1..BATCH]=scores

    float4* rel_out = (float4*)d_ws;   // 8 KB

    rescal_mfma_kernel<<<RELN, 512, 0, stream>>>(
        r_idx, h_idx, t_idx, labels, ent_w, rel_w, out + 1, rel_out);
    final_kernel<<<1, 256, 0, stream>>>(rel_out, out);
}

// Round 20
// 26.750 us; speedup vs baseline: 2.1283x; 1.0140x over previous
//
#include <hip/hip_runtime.h>

#define DIM    128
#define BATCH  16384
#define RELN   500
#define ALPHA  0.001f
#define EB     64                       // elements per batch (mean n=32.8 -> 1 batch)
#define MAXN   640                      // elist capacity (15+ sigma)

typedef __bf16 bf16x8 __attribute__((ext_vector_type(8)));
typedef float  f32x4  __attribute__((ext_vector_type(4)));

__device__ __forceinline__ float dot4(float4 a, float4 b) {
    return a.x * b.x + a.y * b.y + a.z * b.z + a.w * b.w;
}

struct bfx4 { __bf16 a, b, c, d; };
__device__ __forceinline__ bfx4 cvt4(float4 v) {
    bfx4 r; r.a = (__bf16)v.x; r.b = (__bf16)v.y; r.c = (__bf16)v.z; r.d = (__bf16)v.w;
    return r;
}

// ---------- K1: main — one 512-thread block per relation; self-bucketing ----------
// R loads issued BEFORE the r_idx scan (HBM latency hidden under the scan);
// EB=64 -> one {gather, MFMA, epilogue} round for essentially all relations.
// MFMA 16x16x32 (A = R row-tile, B = T cols), epilogue s_j = sum_rows H*Rt.
// Deterministic: per-element scores exact, fixed MFMA K-order.
__global__ void __launch_bounds__(512) rescal_mfma_kernel(
    const int*   __restrict__ r_idx,
    const int*   __restrict__ h_idx,
    const int*   __restrict__ t_idx,
    const float* __restrict__ labels,
    const float* __restrict__ ent_w,
    const float* __restrict__ rel_w,
    float*       __restrict__ scores_out,  // d_out + 1
    float4*      __restrict__ rel_out)     // [RELN] (errS, htS, n*r2, 0)
{
    const int rel = blockIdx.x;
    const int tid = threadIdx.x;
    const int w   = tid >> 6;      // 0..7
    const int l   = tid & 63;

    __shared__ __align__(16) __bf16 Rbf[DIM][136];   // 34816 B
    __shared__ __align__(16) __bf16 Tbf[EB][136];    // 17408 B
    __shared__ __align__(16) __bf16 Hbf[EB][136];    // 17408 B
    __shared__ int   elist[MAXN];                    //  2560 B
    __shared__ int   ncnt;
    __shared__ float s_red[8][EB];                   //  2048 B
    __shared__ int   bidx[EB];
    __shared__ float blab[EB];
    __shared__ float rw_[8], hw_[8], dw_[8];

    if (tid == 0) ncnt = 0;
    __syncthreads();                           // ncnt=0 visible

    // ---- issue R loads first (latency hides under the scan below) ----
    const float4* Rg = (const float4*)(rel_w + (size_t)rel * (DIM * DIM));
    float4 v[8];
    #pragma unroll
    for (int it = 0; it < 8; ++it)
        v[it] = Rg[it * 512 + tid];

    // ---- self-bucket: scan r_idx, collect own elements ----
    for (int i = tid; i < BATCH; i += 512) {
        if (r_idx[i] == rel) {
            const int p = atomicAdd(&ncnt, 1);
            if (p < MAXN) elist[p] = i;
        }
    }

    // ---- consume R: fp32 r2, bf16 into padded LDS ----
    float r2 = 0.f;
    #pragma unroll
    for (int it = 0; it < 8; ++it) {
        const int f = it * 512 + tid;          // float4 index
        r2 += dot4(v[it], v[it]);
        *(bfx4*)&Rbf[f >> 5][(f & 31) * 4] = cvt4(v[it]);
    }
    __syncthreads();                           // Rbf + elist ready
    const int n = ncnt;

    if (n == 0) {
        if (tid == 0) rel_out[rel] = make_float4(0.f, 0.f, 0.f, 0.f);
        return;
    }

    float ht_run = 0.f;      // part==0 threads accumulate per-elem h2+t2
    float d2_run = 0.f;      // wave0 lanes accumulate (s-label)^2

    const int elem = tid >> 3;     // 0..63 (8 threads per element)
    const int part = tid & 7;      // 4 float4 each

    const int nb = (n + EB - 1) / EB;
    for (int bt = 0; bt < nb; ++bt) {
        const int nb_e = min(EB, n - bt * EB);

        // ---- stage T/H for this batch (direct gather) ----
        if (elem < nb_e) {
            const int b  = elist[bt * EB + elem];
            const int hi = h_idx[b];            // same-addr broadcast loads
            const int ti = t_idx[b];
            const float4* hp = (const float4*)(ent_w + (size_t)hi * DIM) + part * 4;
            const float4* tp = (const float4*)(ent_w + (size_t)ti * DIM) + part * 4;
            float htp = 0.f;
            #pragma unroll
            for (int j = 0; j < 4; ++j) {
                const float4 tv = tp[j];
                const float4 hv = hp[j];
                htp += dot4(tv, tv) + dot4(hv, hv);
                *(bfx4*)&Tbf[elem][part * 16 + j * 4] = cvt4(tv);
                *(bfx4*)&Hbf[elem][part * 16 + j * 4] = cvt4(hv);
            }
            #pragma unroll
            for (int off = 4; off >= 1; off >>= 1) htp += __shfl_xor(htp, off);
            if (part == 0) {
                bidx[elem] = b;
                blab[elem] = labels[b];
                ht_run += htp;
            }
        }
        __syncthreads();                                    // B1

        // ---- compute: wave w owns row-tile w (rows 16w..16w+15) ----
        float ps[4] = {0.f, 0.f, 0.f, 0.f};
        #pragma unroll
        for (int ct = 0; ct < 4; ++ct) {
            if (ct * 16 >= nb_e) break;                     // uniform
            f32x4 c = {0.f, 0.f, 0.f, 0.f};
            #pragma unroll
            for (int s = 0; s < 4; ++s) {
                const bf16x8 a = *(const bf16x8*)
                    &Rbf[w * 16 + (l & 15)][s * 32 + (l >> 4) * 8];
                const bf16x8 b = *(const bf16x8*)
                    &Tbf[ct * 16 + (l & 15)][s * 32 + (l >> 4) * 8];
                c = __builtin_amdgcn_mfma_f32_16x16x32_bf16(a, b, c, 0, 0, 0);
            }
            // epilogue: col j = ct*16 + (l&15); rows w*16 + 4*(l>>4) + i
            const int jcol = ct * 16 + (l & 15);
            const int rw0  = w * 16 + 4 * (l >> 4);
            ps[ct] = (float)Hbf[jcol][rw0 + 0] * c[0]
                   + (float)Hbf[jcol][rw0 + 1] * c[1]
                   + (float)Hbf[jcol][rw0 + 2] * c[2]
                   + (float)Hbf[jcol][rw0 + 3] * c[3];
        }
        #pragma unroll
        for (int ct = 0; ct < 4; ++ct) {
            ps[ct] += __shfl_xor(ps[ct], 16);
            ps[ct] += __shfl_xor(ps[ct], 32);
        }
        if (l < 16) {
            #pragma unroll
            for (int ct = 0; ct < 4; ++ct)
                s_red[w][ct * 16 + l] = ps[ct];
        }

        // wave0 pre-reads idx/label (stable since B1; rewritten only after B2)
        int   rb = 0; float lb = 0.f;
        if (w == 0) { rb = bidx[l]; lb = blab[l]; }
        __syncthreads();                                    // B2

        // ---- wave-0 epilogue: full scores + d^2 accumulation ----
        if (w == 0 && l < nb_e) {
            float s = 0.f;
            #pragma unroll
            for (int u = 0; u < 8; ++u) s += s_red[u][l];
            scores_out[rb] = s;
            const float d = s - lb;
            d2_run += d * d;
        }
        // next staging overwrites Tbf/Hbf/bidx: all compute reads were pre-B2;
        // s_red rewritten only after next B1.
    }

    // ---- block reduction of r2 / ht / d2 ----
    float v0 = r2, v1 = ht_run, v2 = d2_run;
    #pragma unroll
    for (int off = 32; off >= 1; off >>= 1) {
        v0 += __shfl_xor(v0, off);
        v1 += __shfl_xor(v1, off);
        v2 += __shfl_xor(v2, off);
    }
    if (l == 0) { rw_[w] = v0; hw_[w] = v1; dw_[w] = v2; }
    __syncthreads();
    if (tid == 0) {
        float r2t = 0.f, htt = 0.f, d2t = 0.f;
        #pragma unroll
        for (int u = 0; u < 8; ++u) { r2t += rw_[u]; htt += hw_[u]; d2t += dw_[u]; }
        rel_out[rel] = make_float4(d2t, htt, (float)n * r2t, 0.f);
    }
}

// ---------- K2: final — fixed-order reduction over rel_out -> loss ----------
__global__ void __launch_bounds__(256) final_kernel(
    const float4* __restrict__ rel_out,
    float*        __restrict__ loss_out)
{
    const int tid = threadIdx.x;
    float err = 0.f, ht = 0.f, r2 = 0.f;
    for (int i = tid; i < RELN; i += 256) {
        const float4 c = rel_out[i];
        err += c.x; ht += c.y; r2 += c.z;
    }
    __shared__ float re[4], rh[4], rr2[4];
    #pragma unroll
    for (int off = 32; off >= 1; off >>= 1) {
        err += __shfl_down(err, off);
        ht  += __shfl_down(ht, off);
        r2  += __shfl_down(r2, off);
    }
    if ((tid & 63) == 0) { const int v = tid >> 6; re[v] = err; rh[v] = ht; rr2[v] = r2; }
    __syncthreads();
    if (tid == 0) {
        err = re[0] + re[1] + re[2] + re[3];
        ht  = rh[0] + rh[1] + rh[2] + rh[3];
        r2  = rr2[0] + rr2[1] + rr2[2] + rr2[3];
        const float mse   = err / (float)BATCH;
        const float norms = (ht / ((float)BATCH * DIM)
                           + r2 / ((float)BATCH * (float)(DIM * DIM))) / 3.0f;
        loss_out[0] = mse + ALPHA * norms;
    }
}

extern "C" void kernel_launch(void* const* d_in, const int* in_sizes, int n_in,
                              void* d_out, int out_size, void* d_ws, size_t ws_size,
                              hipStream_t stream) {
    const int*   h_idx  = (const int*)d_in[0];
    const int*   r_idx  = (const int*)d_in[1];
    const int*   t_idx  = (const int*)d_in[2];
    const float* labels = (const float*)d_in[3];
    const float* ent_w  = (const float*)d_in[4];
    const float* rel_w  = (const float*)d_in[5];

    float* out = (float*)d_out;   // [0]=loss, [1..BATCH]=scores

    float4* rel_out = (float4*)d_ws;   // 8 KB

    rescal_mfma_kernel<<<RELN, 512, 0, stream>>>(
        r_idx, h_idx, t_idx, labels, ent_w, rel_w, out + 1, rel_out);
    final_kernel<<<1, 256, 0, stream>>>(rel_out, out);
}